// Round 6
// baseline (1489.374 us; speedup 1.0000x reference)
//
#include <hip/hip_runtime.h>
#include <stdint.h>
#include <stddef.h>

// ---------------- problem constants ----------------
#define BB   8
#define LL   128
#define DD   768
#define HH   300
#define G4   1200     // 4*H
#define NSP  630      // number of spans
#define FFD  150
#define NZK  64       // top-k

// LSTM persistent-kernel geometry: 30 WGs/dir, 640 threads (10 waves),
// wave w owns h-row j0+w; 16 k-segments of 20 floats per wave.
#define WPD  30
#define JC   10

__device__ __forceinline__ float sigm(float x){ return 1.0f/(1.0f+expf(-x)); }

__device__ __forceinline__ void span_decode(int s, int& w, int& i){
  if      (s < 128){ w=1; i=s; }
  else if (s < 255){ w=2; i=s-128; }
  else if (s < 381){ w=3; i=s-255; }
  else if (s < 506){ w=4; i=s-381; }
  else             { w=5; i=s-506; }
}

__device__ __forceinline__ uint64_t shfl_xor_u64(uint64_t v, int m){
  uint32_t lo = (uint32_t)v, hi = (uint32_t)(v >> 32);
  lo = (uint32_t)__shfl_xor((int)lo, m, 64);
  hi = (uint32_t)__shfl_xor((int)hi, m, 64);
  return ((uint64_t)hi << 32) | lo;
}

// MALL-coherent 16B load (2 tagged u64: {val0,tag0,val1,tag1} as float4)
__device__ __forceinline__ float4 cload16(const unsigned long long* p){
  float4 v;
  asm volatile("global_load_dwordx4 %0, %1, off sc0 sc1\n\ts_waitcnt vmcnt(0)"
               : "=v"(v) : "v"(p) : "memory");
  return v;
}

// ---------------- K1: xg = Wih @ x + bih + bhh  (both dirs) + const partials ----------------
// z==0/1: GEMM, xg layout [dir][t][1200][8].  z==2: width-emb & dist-emb partials.
__global__ __launch_bounds__(256) void k_xg(
    const float* __restrict__ x,
    const float* __restrict__ WihF, const float* __restrict__ bihF, const float* __restrict__ bhhF,
    const float* __restrict__ WihB, const float* __restrict__ bihB, const float* __restrict__ bhhB,
    float* __restrict__ xg,
    const float* __restrict__ sw1, const float* __restrict__ wemb, float* __restrict__ wcst,
    const float* __restrict__ pw1, const float* __restrict__ demb, float* __restrict__ Zd)
{
  if (blockIdx.z == 2) {
    int cb = blockIdx.y*19 + blockIdx.x;
    int n = threadIdx.x;
    if (n < FFD) {
      if (cb < 6) {
        float a = 0.f;
        for (int k=0;k<20;k++) a = fmaf(sw1[n*1220 + 1200 + k], wemb[cb*20 + k], a);
        wcst[cb*FFD + n] = a;
      } else if (cb < 262) {
        int d = cb - 6;
        float a = 0.f;
        for (int k=0;k<128;k++) a = fmaf(pw1[n*2568 + 2440 + k], demb[d*128 + k], a);
        Zd[d*FFD + n] = a;
      }
    }
    return;
  }
  const int dir = blockIdx.z;
  const float* Wih = dir ? WihB : WihF;
  const float* bi  = dir ? bihB : bihF;
  const float* bh  = dir ? bhhB : bhhF;
  const int r0 = blockIdx.x * 64;
  const int n0 = blockIdx.y * 64;   // n = t*8 + b
  __shared__ __align__(16) float As[16*68];
  __shared__ __align__(16) float Bs[16*68];
  const int tid = threadIdx.x;
  const int rl = tid >> 2, kq = tid & 3;
  const int tx = tid & 15, ty = tid >> 4;
  float acc[4][4] = {};
  for (int k0 = 0; k0 < DD; k0 += 16) {
    float4 a4 = make_float4(0.f,0.f,0.f,0.f);
    int ra = r0 + rl;
    if (ra < G4) a4 = *(const float4*)&Wih[ra*DD + k0 + kq*4];
    As[(kq*4+0)*68 + rl] = a4.x;
    As[(kq*4+1)*68 + rl] = a4.y;
    As[(kq*4+2)*68 + rl] = a4.z;
    As[(kq*4+3)*68 + rl] = a4.w;
    int n = n0 + rl; int tt = n >> 3, bb = n & 7;
    float4 b4 = *(const float4*)&x[(bb*LL + tt)*DD + k0 + kq*4];
    Bs[(kq*4+0)*68 + rl] = b4.x;
    Bs[(kq*4+1)*68 + rl] = b4.y;
    Bs[(kq*4+2)*68 + rl] = b4.z;
    Bs[(kq*4+3)*68 + rl] = b4.w;
    __syncthreads();
    #pragma unroll
    for (int kk = 0; kk < 16; ++kk) {
      float4 av = *(const float4*)&As[kk*68 + tx*4];
      float4 bv = *(const float4*)&Bs[kk*68 + ty*4];
      float a_[4] = {av.x,av.y,av.z,av.w};
      float b_[4] = {bv.x,bv.y,bv.z,bv.w};
      #pragma unroll
      for (int i=0;i<4;i++)
        #pragma unroll
        for (int j=0;j<4;j++)
          acc[i][j] = fmaf(a_[i], b_[j], acc[i][j]);
    }
    __syncthreads();
  }
  #pragma unroll
  for (int i=0;i<4;i++){
    int r = r0 + tx*4 + i;
    if (r >= G4) continue;
    float bias = bi[r] + bh[r];
    #pragma unroll
    for (int j=0;j<4;j++){
      int n = n0 + ty*4 + j; int tt = n>>3, bb = n&7;
      xg[((dir*LL + tt)*G4 + r)*8 + bb] = acc[i][j] + bias;
    }
  }
}

// ---------------- K2: persistent bidirectional LSTM ----------------
// 60 wg (30/dir), 640 threads. Wave w owns h-row j = wid*10+w (4 gate rows
// via rl=lane>>4), Whh slice in regs (5 f4/thread).
// h exchange: SELF-TAGGED u64 per value ((step<<32)|bits), relaxed agent
// (sc1) stores fire-and-forget; consumers bulk-read 16B chunks (2 vals+tags)
// with sc0 sc1 dwordx4 and re-read only stale chunks. Parity double-buffer
// closes the overwrite race (a parity is re-entered only after all WGs
// consumed the prior step in it); exact tag match forbids mixed reads.
// 0xAA poison is a non-matching tag -> no clear kernel needed.
// ONE barrier/step (hls parity double-buffered; laggards safe: fill(t+2)
// happens after B1(t+1) which happens after all compute(t)).
__global__ __launch_bounds__(640) void k_lstm(
    const float* __restrict__ WhhF, const float* __restrict__ WhhB,
    const float* __restrict__ xg,
    unsigned long long* __restrict__ hpkt,  // [2 parity][2 dir][2432] u64
    float* __restrict__ out)                // [b][t][600]
{
  const int wg  = blockIdx.x;
  const int dir = wg / WPD;
  const int wid = wg - dir*WPD;
  const int j0  = wid * JC;
  const float* Whh = dir ? WhhB : WhhF;
  unsigned long long* hp = hpkt + (size_t)dir*2432;   // + parity*4864

  __shared__ __align__(16) float hls[2*2448];

  const int tid  = threadIdx.x;   // 0..639
  const int wv   = tid >> 6;      // wave id -> local j
  const int lane = tid & 63;
  const int rl   = lane >> 4;     // gate 0..3
  const int s    = lane & 15;     // k-segment (20 floats)
  const int jj   = j0 + wv;       // h index 0..299
  const int Rabs = rl*HH + jj;
  const int bb   = s & 7;

  // register-resident Whh slice: 20 floats (5 float4) per thread
  float4 w4[5];
  #pragma unroll
  for (int q=0;q<5;q++){
    int k = s*20 + q*4;
    if (k + 3 < HH) w4[q] = *(const float4*)&Whh[(size_t)Rabs*HH + k];
    else            w4[q] = make_float4(0.f,0.f,0.f,0.f);
  }
  float creg = 0.f;               // cell state, valid on lanes<8 (b=lane)
  {                               // zero both hls parities (incl. pads)
    float4* h4 = (float4*)hls;
    for (int i = tid; i < 1224; i += 640) h4[i] = make_float4(0.f,0.f,0.f,0.f);
  }
  __syncthreads();

  float xg_c = xg[((size_t)(dir*LL + (dir ? LL-1 : 0))*G4 + Rabs)*8 + bb];

  for (int t = 0; t < LL; ++t) {
    const int tOrig = dir ? (LL-1 - t) : t;
    // prefetch next step's xg (overlaps exchange latency)
    float xg_n = 0.f;
    if (t+1 < LL) {
      int tO2 = dir ? (LL-2 - t) : (t+1);
      xg_n = xg[((size_t)(dir*LL + tO2)*G4 + Rabs)*8 + bb];
    }
    if (t > 0) {
      const int par = t & 1;
      if (tid < 608) {
        const int f0 = 4*tid;               // float index base (u64 idx == float idx)
        float4 a  = make_float4(0.f,0.f,0.f,0.f);
        float4 b2 = make_float4(0.f,0.f,0.f,0.f);
        if ((f0 % 304) != 300) {            // skip pad chunk (stays zero)
          const unsigned long long* p0 = hp + (size_t)par*4864 + f0;
          const unsigned want = (unsigned)t;
          a  = cload16(p0);
          b2 = cload16(p0 + 2);
          bool ok0 = (__float_as_uint(a.y)==want)  & (__float_as_uint(a.w)==want);
          bool ok1 = (__float_as_uint(b2.y)==want) & (__float_as_uint(b2.w)==want);
          while (!(ok0 & ok1)) {
            __builtin_amdgcn_s_sleep(1);
            if (!ok0) { a  = cload16(p0);     ok0 = (__float_as_uint(a.y)==want)  & (__float_as_uint(a.w)==want); }
            if (!ok1) { b2 = cload16(p0 + 2); ok1 = (__float_as_uint(b2.y)==want) & (__float_as_uint(b2.w)==want); }
          }
        }
        *(float4*)&hls[par*2448 + f0] = make_float4(a.x, a.z, b2.x, b2.z);
      }
    }
    __syncthreads();                        // B1: hls[par] ready
    // partial dot products (4 gate rows/wave broadcast-share each LDS word)
    const float4* h4 = (const float4*)&hls[(t&1)*2448];
    float p[8];
    #pragma unroll
    for (int b=0;b<8;b++){
      const float4* hb = h4 + b*76 + s*5;   // 304 floats = 76 f4 per row
      float ax=0.f, ay=0.f, az=0.f, aw=0.f;
      #pragma unroll
      for (int q=0;q<5;q++){
        float4 hv = hb[q];
        ax = fmaf(w4[q].x, hv.x, ax);
        ay = fmaf(w4[q].y, hv.y, ay);
        az = fmaf(w4[q].z, hv.z, az);
        aw = fmaf(w4[q].w, hv.w, aw);
      }
      p[b] = (ax+ay)+(az+aw);
    }
    // butterfly reduce-scatter over the 16 s-lanes
    #pragma unroll
    for (int b=0;b<8;b++) p[b] += __shfl_xor(p[b], 8, 64);
    float q4[4];
    #pragma unroll
    for (int b=0;b<4;b++){
      float mine = (s&4) ? p[b+4] : p[b];
      float oth  = (s&4) ? p[b]   : p[b+4];
      q4[b] = mine + __shfl_xor(oth, 4, 64);
    }
    float q2[2];
    #pragma unroll
    for (int b=0;b<2;b++){
      float mine = (s&2) ? q4[b+2] : q4[b];
      float oth  = (s&2) ? q4[b]   : q4[b+2];
      q2[b] = mine + __shfl_xor(oth, 2, 64);
    }
    float gv;
    {
      float mine = (s&1) ? q2[1] : q2[0];
      float oth  = (s&1) ? q2[0] : q2[1];
      gv = mine + __shfl_xor(oth, 1, 64) + xg_c;  // valid on s<8 (b=s)
    }
    // gather the 4 gates of (j=jj, b) in-wave; publish tagged h
    {
      int bsel = lane & 7;
      float g_i = __shfl(gv,      bsel, 64);
      float g_f = __shfl(gv, 16 + bsel, 64);
      float g_g = __shfl(gv, 32 + bsel, 64);
      float g_o = __shfl(gv, 48 + bsel, 64);
      if (lane < 8) {
        int b = lane;
        float ig = sigm(g_i), fg = sigm(g_f), gg = tanhf(g_g), og = sigm(g_o);
        creg = fg * creg + ig * gg;
        float h = og * tanhf(creg);
        out[((size_t)(b*LL + tOrig))*600 + dir*HH + jj] = h;
        if (t+1 < LL) {
          unsigned long long pkt =
            ((unsigned long long)(unsigned)(t+1) << 32) |
            (unsigned long long)__float_as_uint(h);
          __hip_atomic_store(&hp[(size_t)(((t+1)&1))*4864 + b*304 + jj], pkt,
                             __ATOMIC_RELAXED, __HIP_MEMORY_SCOPE_AGENT);
        }
      }
    }
    xg_c = xg_n;   // no second barrier: next fill targets the other parity
  }
}

// ---------------- K3a: U/V partial span projections ----------------
__global__ __launch_bounds__(320) void k_uv(
    const float* __restrict__ out, const float* __restrict__ sw1, float* __restrict__ UV)
{
  const int half = blockIdx.z;
  const int row0 = blockIdx.x * 32;
  __shared__ float As[16*36];
  __shared__ __align__(16) float Wt[16*172];
  const int tid = threadIdx.x;
  const int pg = tid / 20, ng = tid - (tid/20)*20;
  float acc[2][8] = {};
  for (int k0 = 0; k0 < 600; k0 += 16) {
    for (int idx = tid; idx < 512; idx += 320) {
      int p = idx >> 4, kk = idx & 15;
      int k = k0 + kk;
      As[kk*36 + p] = (k < 600) ? out[(row0 + p)*600 + k] : 0.f;
    }
    for (int idx = tid; idx < 16*160; idx += 320) {
      int n = idx >> 4, kk = idx & 15;
      int k = k0 + kk;
      Wt[kk*172 + n] = (n < FFD && k < 600) ? sw1[n*1220 + half*600 + k] : 0.f;
    }
    __syncthreads();
    #pragma unroll
    for (int kk=0;kk<16;kk++){
      float2 a2 = *(const float2*)&As[kk*36 + pg*2];
      float4 w0 = *(const float4*)&Wt[kk*172 + ng*8];
      float4 w1 = *(const float4*)&Wt[kk*172 + ng*8 + 4];
      float a_[2] = {a2.x, a2.y};
      float w_[8] = {w0.x,w0.y,w0.z,w0.w,w1.x,w1.y,w1.z,w1.w};
      #pragma unroll
      for (int i=0;i<2;i++)
        #pragma unroll
        for (int j=0;j<8;j++)
          acc[i][j] = fmaf(a_[i], w_[j], acc[i][j]);
    }
    __syncthreads();
  }
  #pragma unroll
  for (int i=0;i<2;i++){
    int row = row0 + pg*2 + i;
    #pragma unroll
    for (int j=0;j<8;j++){
      int n = ng*8 + j;
      if (n < FFD) UV[row*300 + half*FFD + n] = acc[i][j];
    }
  }
}

// ---------------- K3b: span head (z1 combine -> layer2 -> layer3 -> softmax) ----------------
__global__ __launch_bounds__(320) void k_spanhead(
    const float* __restrict__ UV, const float* __restrict__ wcst,
    const float* __restrict__ sb1,
    const float* __restrict__ sw2, const float* __restrict__ sb2,
    const float* __restrict__ sw3, const float* __restrict__ sb3,
    float* __restrict__ sp)
{
  const int b  = blockIdx.y;
  const int s0 = blockIdx.x * 64;
  __shared__ __align__(16) float z1T[160*68];
  __shared__ __align__(16) float z2T[160*68];
  __shared__ __align__(16) float Wt[16*172];
  __shared__ float zf[256];
  __shared__ int sI[64], sJ[64], sW[64];
  const int tid = threadIdx.x;
  if (tid < 64) {
    int s = s0 + tid; int w = 1, i0 = 0;
    if (s < NSP) span_decode(s, w, i0);
    sI[tid] = i0; sJ[tid] = i0 + w - 1; sW[tid] = w;
  }
  __syncthreads();
  for (int idx = tid; idx < 64*160; idx += 320) {
    int p = idx / 160, k = idx - p*160;
    float v = 0.f;
    if (k < FFD && (s0 + p) < NSP) {
      v = UV[(b*LL + sI[p])*300 + k] + UV[(b*LL + sJ[p])*300 + FFD + k]
        + wcst[sW[p]*FFD + k] + sb1[k];
      v = fmaxf(v, 0.f);
    }
    z1T[k*68 + p] = v;
  }
  const int pg = tid / 20, ng = tid - (tid/20)*20;
  float acc[4][8] = {};
  for (int kt = 0; kt < 10; ++kt) {
    __syncthreads();
    for (int idx = tid; idx < 16*160; idx += 320) {
      int n = idx >> 4, kk = idx & 15;
      int k = kt*16 + kk;
      Wt[kk*172 + n] = (n < FFD && k < FFD) ? sw2[n*FFD + k] : 0.f;
    }
    __syncthreads();
    #pragma unroll
    for (int kk = 0; kk < 16; ++kk) {
      float4 a4 = *(const float4*)&z1T[(kt*16+kk)*68 + pg*4];
      float4 w0 = *(const float4*)&Wt[kk*172 + ng*8];
      float4 w1 = *(const float4*)&Wt[kk*172 + ng*8 + 4];
      float a_[4] = {a4.x,a4.y,a4.z,a4.w};
      float w_[8] = {w0.x,w0.y,w0.z,w0.w,w1.x,w1.y,w1.z,w1.w};
      #pragma unroll
      for (int i=0;i<4;i++)
        #pragma unroll
        for (int j=0;j<8;j++)
          acc[i][j] = fmaf(a_[i], w_[j], acc[i][j]);
    }
  }
  __syncthreads();
  #pragma unroll
  for (int j=0;j<8;j++){
    int n = ng*8 + j;
    float bn = (n < FFD) ? sb2[n] : 0.f;
    #pragma unroll
    for (int i=0;i<4;i++){
      float v = (n < FFD) ? fmaxf(acc[i][j] + bn, 0.f) : 0.f;
      z2T[n*68 + pg*4 + i] = v;
    }
  }
  __syncthreads();
  if (tid < 256) {
    int p = tid >> 2, c = tid & 3;
    if (c < 3 && (s0 + p) < NSP) {
      float a = sb3[c];
      for (int k=0;k<FFD;k++) a = fmaf(z2T[k*68 + p], sw3[c*FFD + k], a);
      zf[p*4 + c] = a;
    }
  }
  __syncthreads();
  if (tid < 64 && (s0 + tid) < NSP) {
    float z0 = zf[tid*4], z1 = zf[tid*4+1], z2 = zf[tid*4+2];
    float m = fmaxf(z0, fmaxf(z1, z2));
    float e0 = expf(z0-m), e1 = expf(z1-m), e2 = expf(z2-m);
    float inv = 1.f/(e0+e1+e2);
    int s = s0 + tid;
    sp[(b*NSP + s)*3 + 0] = e0*inv;
    sp[(b*NSP + s)*3 + 1] = e1*inv;
    sp[(b*NSP + s)*3 + 2] = e2*inv;
  }
}

// ---------------- K4: deterministic top-64 (ties -> smaller index) ----------------
__global__ __launch_bounds__(64) void k_topk(
    const float* __restrict__ sp, float* __restrict__ outT, float* __restrict__ outO,
    int* __restrict__ idxw)
{
  const int cls = blockIdx.x >> 3;   // 0: aspect(col1), 1: opinion(col2)
  const int b   = blockIdx.x & 7;
  const int lane = threadIdx.x;
  uint64_t key[10];
  #pragma unroll
  for (int q=0;q<10;q++){
    int s = lane + q*64;
    uint32_t bits = 0u;
    if (s < NSP) bits = __float_as_uint(sp[(b*NSP + s)*3 + 1 + cls]);
    key[q] = ((uint64_t)bits << 32) | (uint32_t)(1023 - s);
  }
  float* dst = cls ? outO : outT;
  for (int r = 0; r < NZK; ++r) {
    uint64_t best = key[0];
    #pragma unroll
    for (int q=1;q<10;q++) best = key[q] > best ? key[q] : best;
    #pragma unroll
    for (int off = 32; off > 0; off >>= 1) {
      uint64_t o = shfl_xor_u64(best, off);
      best = o > best ? o : best;
    }
    int sWin = 1023 - (int)(best & 0xFFFFFFFFu);
    if ((sWin & 63) == lane) {
      int qw = sWin >> 6;
      #pragma unroll
      for (int q=0;q<10;q++) if (q == qw) key[q] = 0;
    }
    if (lane == 0) {
      dst[b*NZK + r] = (float)sWin;
      idxw[cls*512 + b*NZK + r] = sWin;
    }
  }
}

// ---------------- K5a: Zt/Zo partial pair projections over selected spans ----------------
__global__ __launch_bounds__(320) void k_zto(
    const float* __restrict__ out, const float* __restrict__ wemb,
    const float* __restrict__ pw1, const int* __restrict__ idxw,
    float* __restrict__ ZTO)
{
  const int wg = blockIdx.x;
  const int cls = wg >> 5;
  const int rem = wg & 31;
  const int b = rem >> 2;
  const int i0 = (rem & 3) * 16;
  __shared__ float As[16*20];
  __shared__ __align__(16) float Wt[16*172];
  __shared__ int sI[16], sJ[16], sW[16];
  const int tid = threadIdx.x;
  if (tid < 16) {
    int S = idxw[cls*512 + b*64 + i0 + tid];
    int w, i_; span_decode(S, w, i_);
    sI[tid] = i_; sJ[tid] = i_ + w - 1; sW[tid] = w;
  }
  const int pg = tid / 20, ng = tid - (tid/20)*20;
  float acc[8] = {};
  __syncthreads();
  for (int k0 = 0; k0 < 1232; k0 += 16) {
    if (tid < 256) {
      int p = tid >> 4, kk = tid & 15;
      int k = k0 + kk;
      float v = 0.f;
      if      (k < 600)  v = out[(b*LL + sI[p])*600 + k];
      else if (k < 1200) v = out[(b*LL + sJ[p])*600 + (k - 600)];
      else if (k < 1220) v = wemb[sW[p]*20 + (k - 1200)];
      As[kk*20 + p] = v;
    }
    for (int idx = tid; idx < 16*160; idx += 320) {
      int n = idx >> 4, kk = idx & 15;
      int k = k0 + kk;
      Wt[kk*172 + n] = (n < FFD && k < 1220) ? pw1[n*2568 + cls*1220 + k] : 0.f;
    }
    __syncthreads();
    #pragma unroll
    for (int kk=0;kk<16;kk++){
      float a = As[kk*20 + pg];
      float4 w0 = *(const float4*)&Wt[kk*172 + ng*8];
      float4 w1 = *(const float4*)&Wt[kk*172 + ng*8 + 4];
      acc[0] = fmaf(a, w0.x, acc[0]);
      acc[1] = fmaf(a, w0.y, acc[1]);
      acc[2] = fmaf(a, w0.z, acc[2]);
      acc[3] = fmaf(a, w0.w, acc[3]);
      acc[4] = fmaf(a, w1.x, acc[4]);
      acc[5] = fmaf(a, w1.y, acc[5]);
      acc[6] = fmaf(a, w1.z, acc[6]);
      acc[7] = fmaf(a, w1.w, acc[7]);
    }
    __syncthreads();
  }
  #pragma unroll
  for (int j=0;j<8;j++){
    int n = ng*8 + j;
    if (n < FFD) ZTO[(cls*512 + b*64 + i0 + pg)*FFD + n] = acc[j];
  }
}

// ---------------- K5b: pair head ----------------
__global__ __launch_bounds__(320) void k_pairhead(
    const float* __restrict__ ZTO, const float* __restrict__ Zd,
    const float* __restrict__ pb1,
    const float* __restrict__ pw2, const float* __restrict__ pb2,
    const float* __restrict__ pw3, const float* __restrict__ pb3,
    const int* __restrict__ idxw,
    float* __restrict__ cp)
{
  const int b  = blockIdx.y;
  const int ti = blockIdx.x;
  __shared__ __align__(16) float z1T[160*68];
  __shared__ __align__(16) float z2T[160*68];
  __shared__ __align__(16) float Wt[16*172];
  __shared__ float zf[256];
  __shared__ int oDist[64];
  const int tid = threadIdx.x;
  const int tS = idxw[b*64 + ti];
  int wT, iT; span_decode(tS, wT, iT);
  const int aT = iT, bT = iT + wT - 1;
  if (tid < 64) {
    int oS = idxw[512 + b*64 + tid];
    int wO, iO; span_decode(oS, wO, iO);
    int d1 = bT - iO;            if (d1 < 0) d1 = -d1;
    int d2 = aT - (iO + wO - 1); if (d2 < 0) d2 = -d2;
    oDist[tid] = d1 < d2 ? d1 : d2;
  }
  __syncthreads();
  const float* ZtRow = ZTO + (b*64 + ti)*FFD;
  for (int idx = tid; idx < 64*160; idx += 320) {
    int p = idx / 160, k = idx - p*160;
    float v = 0.f;
    if (k < FFD) {
      v = ZtRow[k] + ZTO[(512 + b*64 + p)*FFD + k] + Zd[oDist[p]*FFD + k] + pb1[k];
      v = fmaxf(v, 0.f);
    }
    z1T[k*68 + p] = v;
  }
  const int pg = tid / 20, ng = tid - (tid/20)*20;
  float acc[4][8] = {};
  for (int kt = 0; kt < 10; ++kt) {
    __syncthreads();
    for (int idx = tid; idx < 16*160; idx += 320) {
      int n = idx >> 4, kk = idx & 15;
      int k = kt*16 + kk;
      Wt[kk*172 + n] = (n < FFD && k < FFD) ? pw2[n*FFD + k] : 0.f;
    }
    __syncthreads();
    #pragma unroll
    for (int kk = 0; kk < 16; ++kk) {
      float4 a4 = *(const float4*)&z1T[(kt*16+kk)*68 + pg*4];
      float4 w0 = *(const float4*)&Wt[kk*172 + ng*8];
      float4 w1 = *(const float4*)&Wt[kk*172 + ng*8 + 4];
      float a_[4] = {a4.x,a4.y,a4.z,a4.w};
      float w_[8] = {w0.x,w0.y,w0.z,w0.w,w1.x,w1.y,w1.z,w1.w};
      #pragma unroll
      for (int i=0;i<4;i++)
        #pragma unroll
        for (int j=0;j<8;j++)
          acc[i][j] = fmaf(a_[i], w_[j], acc[i][j]);
    }
  }
  __syncthreads();
  #pragma unroll
  for (int j=0;j<8;j++){
    int n = ng*8 + j;
    float bn = (n < FFD) ? pb2[n] : 0.f;
    #pragma unroll
    for (int i=0;i<4;i++){
      float v = (n < FFD) ? fmaxf(acc[i][j] + bn, 0.f) : 0.f;
      z2T[n*68 + pg*4 + i] = v;
    }
  }
  __syncthreads();
  if (tid < 256) {
    int p = tid >> 2, c = tid & 3;
    float a = pb3[c];
    for (int k=0;k<FFD;k++) a = fmaf(z2T[k*68 + p], pw3[c*FFD + k], a);
    zf[tid] = a;
  }
  __syncthreads();
  if (tid < 64) {
    float z0 = zf[tid*4], z1 = zf[tid*4+1], z2 = zf[tid*4+2], z3 = zf[tid*4+3];
    float m = fmaxf(fmaxf(z0,z1), fmaxf(z2,z3));
    float e0 = expf(z0-m), e1 = expf(z1-m), e2 = expf(z2-m), e3 = expf(z3-m);
    float inv = 1.f/(e0+e1+e2+e3);
    float4 o4 = make_float4(e0*inv, e1*inv, e2*inv, e3*inv);
    *(float4*)&cp[(size_t)((b*4096 + ti*64 + tid))*4] = o4;
  }
}

// ---------------- launch ----------------
extern "C" void kernel_launch(void* const* d_in, const int* in_sizes, int n_in,
                              void* d_out, int out_size, void* d_ws, size_t ws_size,
                              hipStream_t stream) {
  const float* x    = (const float*)d_in[0];
  const float* WihF = (const float*)d_in[1];
  const float* WhhF = (const float*)d_in[2];
  const float* bihF = (const float*)d_in[3];
  const float* bhhF = (const float*)d_in[4];
  const float* WihB = (const float*)d_in[5];
  const float* WhhB = (const float*)d_in[6];
  const float* bihB = (const float*)d_in[7];
  const float* bhhB = (const float*)d_in[8];
  const float* wemb = (const float*)d_in[9];
  const float* demb = (const float*)d_in[10];
  const float* sw1  = (const float*)d_in[11];
  const float* sb1  = (const float*)d_in[12];
  const float* sw2  = (const float*)d_in[13];
  const float* sb2  = (const float*)d_in[14];
  const float* sw3  = (const float*)d_in[15];
  const float* sb3  = (const float*)d_in[16];
  const float* pw1  = (const float*)d_in[17];
  const float* pb1  = (const float*)d_in[18];
  const float* pw2  = (const float*)d_in[19];
  const float* pb2  = (const float*)d_in[20];
  const float* pw3  = (const float*)d_in[21];
  const float* pb3  = (const float*)d_in[22];

  uint8_t* wsb = (uint8_t*)d_ws;
  unsigned long long* hpkt = (unsigned long long*)(wsb + 16384); // [2][2][2432] u64 = 77.8 KB
  float* xg    = (float*)(wsb + 131072);           // [2][128][1200][8] = 2457600 f
  float* outh  = xg   + 2457600;                   // [8][128][600]     = 614400 f
  float* UV    = outh + 614400;                    // [1024][300]       = 307200 f
  float* wcst  = UV   + 307200;                    // [6][150]          = 900 f
  float* Zd    = wcst + 900;                       // [256][150]        = 38400 f
  float* ZTO   = Zd   + 38400;                     // [1024][150]       = 153600 f
  int*  idxw   = (int*)(ZTO + 153600);             // [2][8][64]        = 1024 i

  float* o   = (float*)d_out;
  float* spO = o;              // [8][630][3]  = 15120
  float* cpO = o + 15120;      // [8][4096][4] = 131072
  float* tO  = o + 146192;     // [8][64]
  float* oO  = o + 146704;     // [8][64]

  k_xg      <<<dim3(19,16,3), 256, 0, stream>>>(x, WihF, bihF, bhhF, WihB, bihB, bhhB, xg,
                                                sw1, wemb, wcst, pw1, demb, Zd);
  k_lstm    <<<dim3(2*WPD), 640, 0, stream>>>(WhhF, WhhB, xg, hpkt, outh);
  k_uv      <<<dim3(32,1,2), 320, 0, stream>>>(outh, sw1, UV);
  k_spanhead<<<dim3(10,8), 320, 0, stream>>>(UV, wcst, sb1, sw2, sb2, sw3, sb3, spO);
  k_topk    <<<dim3(16),  64, 0, stream>>>(spO, tO, oO, idxw);
  k_zto     <<<dim3(64),  320, 0, stream>>>(outh, wemb, pw1, idxw, ZTO);
  k_pairhead<<<dim3(64,8), 320, 0, stream>>>(ZTO, Zd, pb1, pw2, pb2, pw3, pb3, idxw, cpO);
}

// Round 7
// 1468.102 us; speedup vs baseline: 1.0145x; 1.0145x over previous
//
#include <hip/hip_runtime.h>
#include <stdint.h>
#include <stddef.h>

// ---------------- problem constants ----------------
#define BB   8
#define LL   128
#define DD   768
#define HH   300
#define G4   1200     // 4*H
#define NSP  630      // number of spans
#define FFD  150
#define NZK  64       // top-k

// LSTM persistent-kernel geometry: 60 WGs/dir, 320 threads (5 waves),
// wave w owns h-row j0+w; 16 k-segments of 20 floats per wave.
#define WPD  60
#define JC   5

__device__ __forceinline__ float sigm(float x){ return 1.0f/(1.0f+expf(-x)); }

__device__ __forceinline__ void span_decode(int s, int& w, int& i){
  if      (s < 128){ w=1; i=s; }
  else if (s < 255){ w=2; i=s-128; }
  else if (s < 381){ w=3; i=s-255; }
  else if (s < 506){ w=4; i=s-381; }
  else             { w=5; i=s-506; }
}

__device__ __forceinline__ uint64_t shfl_xor_u64(uint64_t v, int m){
  uint32_t lo = (uint32_t)v, hi = (uint32_t)(v >> 32);
  lo = (uint32_t)__shfl_xor((int)lo, m, 64);
  hi = (uint32_t)__shfl_xor((int)hi, m, 64);
  return ((uint64_t)hi << 32) | lo;
}

// ---------------- K1: xg = Wih @ x + bih + bhh  (both dirs) + const partials ----------------
// z==0/1: GEMM, xg layout [dir][t][1200][8].  z==2: width-emb & dist-emb partials.
// Block (0,0,0) zeroes the 120 per-WG step counters (sc1 stores; kernel
// completion orders them before k_lstm's agent-scope polls).
__global__ __launch_bounds__(256) void k_xg(
    const float* __restrict__ x,
    const float* __restrict__ WihF, const float* __restrict__ bihF, const float* __restrict__ bhhF,
    const float* __restrict__ WihB, const float* __restrict__ bihB, const float* __restrict__ bhhB,
    float* __restrict__ xg, unsigned int* __restrict__ tags,
    const float* __restrict__ sw1, const float* __restrict__ wemb, float* __restrict__ wcst,
    const float* __restrict__ pw1, const float* __restrict__ demb, float* __restrict__ Zd)
{
  if (blockIdx.z == 2) {
    int cb = blockIdx.y*19 + blockIdx.x;
    int n = threadIdx.x;
    if (n < FFD) {
      if (cb < 6) {
        float a = 0.f;
        for (int k=0;k<20;k++) a = fmaf(sw1[n*1220 + 1200 + k], wemb[cb*20 + k], a);
        wcst[cb*FFD + n] = a;
      } else if (cb < 262) {
        int d = cb - 6;
        float a = 0.f;
        for (int k=0;k<128;k++) a = fmaf(pw1[n*2568 + 2440 + k], demb[d*128 + k], a);
        Zd[d*FFD + n] = a;
      }
    }
    return;
  }
  if (blockIdx.x==0 && blockIdx.y==0 && blockIdx.z==0) {
    for (int i = threadIdx.x; i < 2*60*32; i += 256)
      __hip_atomic_store(&tags[i], 0u, __ATOMIC_RELAXED, __HIP_MEMORY_SCOPE_AGENT);
  }
  const int dir = blockIdx.z;
  const float* Wih = dir ? WihB : WihF;
  const float* bi  = dir ? bihB : bihF;
  const float* bh  = dir ? bhhB : bhhF;
  const int r0 = blockIdx.x * 64;
  const int n0 = blockIdx.y * 64;   // n = t*8 + b
  __shared__ __align__(16) float As[16*68];
  __shared__ __align__(16) float Bs[16*68];
  const int tid = threadIdx.x;
  const int rl = tid >> 2, kq = tid & 3;
  const int tx = tid & 15, ty = tid >> 4;
  float acc[4][4] = {};
  for (int k0 = 0; k0 < DD; k0 += 16) {
    float4 a4 = make_float4(0.f,0.f,0.f,0.f);
    int ra = r0 + rl;
    if (ra < G4) a4 = *(const float4*)&Wih[ra*DD + k0 + kq*4];
    As[(kq*4+0)*68 + rl] = a4.x;
    As[(kq*4+1)*68 + rl] = a4.y;
    As[(kq*4+2)*68 + rl] = a4.z;
    As[(kq*4+3)*68 + rl] = a4.w;
    int n = n0 + rl; int tt = n >> 3, bb = n & 7;
    float4 b4 = *(const float4*)&x[(bb*LL + tt)*DD + k0 + kq*4];
    Bs[(kq*4+0)*68 + rl] = b4.x;
    Bs[(kq*4+1)*68 + rl] = b4.y;
    Bs[(kq*4+2)*68 + rl] = b4.z;
    Bs[(kq*4+3)*68 + rl] = b4.w;
    __syncthreads();
    #pragma unroll
    for (int kk = 0; kk < 16; ++kk) {
      float4 av = *(const float4*)&As[kk*68 + tx*4];
      float4 bv = *(const float4*)&Bs[kk*68 + ty*4];
      float a_[4] = {av.x,av.y,av.z,av.w};
      float b_[4] = {bv.x,bv.y,bv.z,bv.w};
      #pragma unroll
      for (int i=0;i<4;i++)
        #pragma unroll
        for (int j=0;j<4;j++)
          acc[i][j] = fmaf(a_[i], b_[j], acc[i][j]);
    }
    __syncthreads();
  }
  #pragma unroll
  for (int i=0;i<4;i++){
    int r = r0 + tx*4 + i;
    if (r >= G4) continue;
    float bias = bi[r] + bh[r];
    #pragma unroll
    for (int j=0;j<4;j++){
      int n = n0 + ty*4 + j; int tt = n>>3, bb = n&7;
      xg[((dir*LL + tt)*G4 + r)*8 + bb] = acc[i][j] + bias;
    }
  }
}

// ---------------- K2: persistent bidirectional LSTM ----------------
// 120 wg (60/dir), 320 threads. Wave w owns h-row j = wid*5+w; Whh slice in
// regs (5 f4/thread).
// Protocol (R5 structure, de-serialized):
//  - h data: plain floats, parity double-buffered [2][2 dir][8][304]; producer
//    lanes<8 store h(t+1) into parity (t+1)&1 with relaxed agent (sc1) stores.
//  - readiness: per-WG COUNTER; each wave drains ITS OWN stores
//    (s_waitcnt vmcnt(0)) then lane0 posts a fire-and-forget atomic add.
//    Consumers poll counter >= 5*t. No WG-wide drain barrier.
//  - out[] HBM store issued AFTER drain+post: its ack lands in the NEXT
//    step's drain (~2us later, free).
//  - ONE barrier/step: hls parity-doubled. Refill of a parity is provably
//    after every WG consumed it (counter 5(t+2) requires all WGs' B1(t+1),
//    which is after their fill(t+1) read).
//  - bulk read: one-shot 2x global_load_dwordx4 sc0 sc1 per thread (no
//    per-chunk tags — R3/R6's request-storm lesson).
__global__ __launch_bounds__(320) void k_lstm(
    const float* __restrict__ WhhF, const float* __restrict__ WhhB,
    const float* __restrict__ xg,
    float* __restrict__ hexf,           // [2 parity][2 dir][2432] floats
    unsigned int* __restrict__ tags,    // [2][60] stride-32 counters
    float* __restrict__ out)            // [b][t][600]
{
  const int wg  = blockIdx.x;
  const int dir = wg / WPD;
  const int wid = wg - dir*WPD;
  const int j0  = wid * JC;
  const float* Whh = dir ? WhhB : WhhF;
  float* hex0 = hexf + (size_t)dir*2432;       // + parity*4864
  unsigned int* tg = tags + dir*60*32;

  __shared__ __align__(16) float hls[2*2448];
  __shared__ int hready;

  const int tid  = threadIdx.x;   // 0..319
  const int wv   = tid >> 6;      // wave id -> local j
  const int lane = tid & 63;
  const int rl   = lane >> 4;     // gate 0..3
  const int s    = lane & 15;     // k-segment (20 floats)
  const int jj   = j0 + wv;       // h index 0..299
  const int Rabs = rl*HH + jj;
  const int bb   = s & 7;

  // register-resident Whh slice: 20 floats (5 float4) per thread
  float4 w4[5];
  #pragma unroll
  for (int q=0;q<5;q++){
    int k = s*20 + q*4;
    if (k + 3 < HH) w4[q] = *(const float4*)&Whh[(size_t)Rabs*HH + k];
    else            w4[q] = make_float4(0.f,0.f,0.f,0.f);
  }
  float creg = 0.f;               // cell state, valid on lanes<8 (b=lane)
  if (tid == 0) hready = 0;
  {                               // zero both hls parities (incl. pads)
    float4* h4 = (float4*)hls;
    for (int i = tid; i < 1224; i += 320) h4[i] = make_float4(0.f,0.f,0.f,0.f);
  }
  __syncthreads();

  float xg_c = xg[((size_t)(dir*LL + (dir ? LL-1 : 0))*G4 + Rabs)*8 + bb];

  for (int t = 0; t < LL; ++t) {
    const int tOrig = dir ? (LL-1 - t) : t;
    // prefetch next step's xg (overlaps exchange latency)
    float xg_n = 0.f;
    if (t+1 < LL) {
      int tO2 = dir ? (LL-2 - t) : (t+1);
      xg_n = xg[((size_t)(dir*LL + tO2)*G4 + Rabs)*8 + bb];
    }
    if (t > 0) {
      const unsigned want = 5u*(unsigned)t;
      // readiness: wave0 polls 60 counter lines; others spin on LDS flag
      if (wv == 0) {
        if (lane < 60) {
          while (__hip_atomic_load(&tg[lane*32], __ATOMIC_RELAXED,
                                   __HIP_MEMORY_SCOPE_AGENT) < want)
            __builtin_amdgcn_s_sleep(1);
        }
        if (lane == 0) ((volatile int*)&hready)[0] = t;
      } else {
        while (((volatile int*)&hready)[0] < t) __builtin_amdgcn_s_sleep(1);
      }
      // one-shot bulk read from parity t&1 (MALL-coherent, no tags)
      if (tid < 304) {
        const int f0 = tid*8;
        const float* p0 = hex0 + (size_t)(t&1)*4864 + f0;
        float4 v0, v1;
        if ((f0 % 304) == 296) {           // mixed chunk: 4 real + 4 pad
          asm volatile(
            "global_load_dwordx4 %0, %1, off sc0 sc1\n\t"
            "s_waitcnt vmcnt(0)"
            : "=v"(v0) : "v"(p0) : "memory");
          v1 = make_float4(0.f,0.f,0.f,0.f);
        } else {
          asm volatile(
            "global_load_dwordx4 %0, %2, off sc0 sc1\n\t"
            "global_load_dwordx4 %1, %3, off sc0 sc1\n\t"
            "s_waitcnt vmcnt(0)"
            : "=v"(v0), "=v"(v1)
            : "v"(p0), "v"(p0 + 4)
            : "memory");
        }
        float4* d = (float4*)&hls[(t&1)*2448 + f0];
        d[0] = v0; d[1] = v1;
      }
    }
    __syncthreads();                        // B1: hls[t&1] ready
    // partial dot products (4 gate rows/wave broadcast-share each LDS word)
    const float4* h4 = (const float4*)&hls[(t&1)*2448];
    float p[8];
    #pragma unroll
    for (int b=0;b<8;b++){
      const float4* hb = h4 + b*76 + s*5;   // 304 floats = 76 f4 per row
      float ax=0.f, ay=0.f, az=0.f, aw=0.f;
      #pragma unroll
      for (int q=0;q<5;q++){
        float4 hv = hb[q];
        ax = fmaf(w4[q].x, hv.x, ax);
        ay = fmaf(w4[q].y, hv.y, ay);
        az = fmaf(w4[q].z, hv.z, az);
        aw = fmaf(w4[q].w, hv.w, aw);
      }
      p[b] = (ax+ay)+(az+aw);
    }
    // butterfly reduce-scatter over the 16 s-lanes
    #pragma unroll
    for (int b=0;b<8;b++) p[b] += __shfl_xor(p[b], 8, 64);
    float q4[4];
    #pragma unroll
    for (int b=0;b<4;b++){
      float mine = (s&4) ? p[b+4] : p[b];
      float oth  = (s&4) ? p[b]   : p[b+4];
      q4[b] = mine + __shfl_xor(oth, 4, 64);
    }
    float q2[2];
    #pragma unroll
    for (int b=0;b<2;b++){
      float mine = (s&2) ? q4[b+2] : q4[b];
      float oth  = (s&2) ? q4[b]   : q4[b+2];
      q2[b] = mine + __shfl_xor(oth, 2, 64);
    }
    float gv;
    {
      float mine = (s&1) ? q2[1] : q2[0];
      float oth  = (s&1) ? q2[0] : q2[1];
      gv = mine + __shfl_xor(oth, 1, 64) + xg_c;  // valid on s<8 (b=s)
    }
    // gather the 4 gates of (j=jj, b) in-wave; compute h
    float hval = 0.f;
    {
      int bsel = lane & 7;
      float g_i = __shfl(gv,      bsel, 64);
      float g_f = __shfl(gv, 16 + bsel, 64);
      float g_g = __shfl(gv, 32 + bsel, 64);
      float g_o = __shfl(gv, 48 + bsel, 64);
      if (lane < 8) {
        float ig = sigm(g_i), fg = sigm(g_f), gg = tanhf(g_g), og = sigm(g_o);
        creg = fg * creg + ig * gg;
        hval = og * tanhf(creg);
        if (t+1 < LL)
          __hip_atomic_store(&hex0[(size_t)(((t+1)&1))*4864 + lane*304 + jj], hval,
                             __ATOMIC_RELAXED, __HIP_MEMORY_SCOPE_AGENT);
      }
    }
    // per-wave drain of own h stores, then fire-and-forget counter add
    asm volatile("s_waitcnt vmcnt(0)" ::: "memory");
    if (t+1 < LL && lane == 0)
      __hip_atomic_fetch_add(&tg[wid*32], 1u,
                             __ATOMIC_RELAXED, __HIP_MEMORY_SCOPE_AGENT);
    // out[] store AFTER the post: its ack lands in next step's drain (free)
    if (lane < 8)
      out[((size_t)(lane*LL + tOrig))*600 + dir*HH + jj] = hval;
    xg_c = xg_n;   // no second barrier: next fill targets the other parity
  }
}

// ---------------- K3a: U/V partial span projections ----------------
__global__ __launch_bounds__(320) void k_uv(
    const float* __restrict__ out, const float* __restrict__ sw1, float* __restrict__ UV)
{
  const int half = blockIdx.z;
  const int row0 = blockIdx.x * 32;
  __shared__ float As[16*36];
  __shared__ __align__(16) float Wt[16*172];
  const int tid = threadIdx.x;
  const int pg = tid / 20, ng = tid - (tid/20)*20;
  float acc[2][8] = {};
  for (int k0 = 0; k0 < 600; k0 += 16) {
    for (int idx = tid; idx < 512; idx += 320) {
      int p = idx >> 4, kk = idx & 15;
      int k = k0 + kk;
      As[kk*36 + p] = (k < 600) ? out[(row0 + p)*600 + k] : 0.f;
    }
    for (int idx = tid; idx < 16*160; idx += 320) {
      int n = idx >> 4, kk = idx & 15;
      int k = k0 + kk;
      Wt[kk*172 + n] = (n < FFD && k < 600) ? sw1[n*1220 + half*600 + k] : 0.f;
    }
    __syncthreads();
    #pragma unroll
    for (int kk=0;kk<16;kk++){
      float2 a2 = *(const float2*)&As[kk*36 + pg*2];
      float4 w0 = *(const float4*)&Wt[kk*172 + ng*8];
      float4 w1 = *(const float4*)&Wt[kk*172 + ng*8 + 4];
      float a_[2] = {a2.x, a2.y};
      float w_[8] = {w0.x,w0.y,w0.z,w0.w,w1.x,w1.y,w1.z,w1.w};
      #pragma unroll
      for (int i=0;i<2;i++)
        #pragma unroll
        for (int j=0;j<8;j++)
          acc[i][j] = fmaf(a_[i], w_[j], acc[i][j]);
    }
    __syncthreads();
  }
  #pragma unroll
  for (int i=0;i<2;i++){
    int row = row0 + pg*2 + i;
    #pragma unroll
    for (int j=0;j<8;j++){
      int n = ng*8 + j;
      if (n < FFD) UV[row*300 + half*FFD + n] = acc[i][j];
    }
  }
}

// ---------------- K3b: span head (z1 combine -> layer2 -> layer3 -> softmax) ----------------
__global__ __launch_bounds__(320) void k_spanhead(
    const float* __restrict__ UV, const float* __restrict__ wcst,
    const float* __restrict__ sb1,
    const float* __restrict__ sw2, const float* __restrict__ sb2,
    const float* __restrict__ sw3, const float* __restrict__ sb3,
    float* __restrict__ sp)
{
  const int b  = blockIdx.y;
  const int s0 = blockIdx.x * 64;
  __shared__ __align__(16) float z1T[160*68];
  __shared__ __align__(16) float z2T[160*68];
  __shared__ __align__(16) float Wt[16*172];
  __shared__ float zf[256];
  __shared__ int sI[64], sJ[64], sW[64];
  const int tid = threadIdx.x;
  if (tid < 64) {
    int s = s0 + tid; int w = 1, i0 = 0;
    if (s < NSP) span_decode(s, w, i0);
    sI[tid] = i0; sJ[tid] = i0 + w - 1; sW[tid] = w;
  }
  __syncthreads();
  for (int idx = tid; idx < 64*160; idx += 320) {
    int p = idx / 160, k = idx - p*160;
    float v = 0.f;
    if (k < FFD && (s0 + p) < NSP) {
      v = UV[(b*LL + sI[p])*300 + k] + UV[(b*LL + sJ[p])*300 + FFD + k]
        + wcst[sW[p]*FFD + k] + sb1[k];
      v = fmaxf(v, 0.f);
    }
    z1T[k*68 + p] = v;
  }
  const int pg = tid / 20, ng = tid - (tid/20)*20;
  float acc[4][8] = {};
  for (int kt = 0; kt < 10; ++kt) {
    __syncthreads();
    for (int idx = tid; idx < 16*160; idx += 320) {
      int n = idx >> 4, kk = idx & 15;
      int k = kt*16 + kk;
      Wt[kk*172 + n] = (n < FFD && k < FFD) ? sw2[n*FFD + k] : 0.f;
    }
    __syncthreads();
    #pragma unroll
    for (int kk = 0; kk < 16; ++kk) {
      float4 a4 = *(const float4*)&z1T[(kt*16+kk)*68 + pg*4];
      float4 w0 = *(const float4*)&Wt[kk*172 + ng*8];
      float4 w1 = *(const float4*)&Wt[kk*172 + ng*8 + 4];
      float a_[4] = {a4.x,a4.y,a4.z,a4.w};
      float w_[8] = {w0.x,w0.y,w0.z,w0.w,w1.x,w1.y,w1.z,w1.w};
      #pragma unroll
      for (int i=0;i<4;i++)
        #pragma unroll
        for (int j=0;j<8;j++)
          acc[i][j] = fmaf(a_[i], w_[j], acc[i][j]);
    }
  }
  __syncthreads();
  #pragma unroll
  for (int j=0;j<8;j++){
    int n = ng*8 + j;
    float bn = (n < FFD) ? sb2[n] : 0.f;
    #pragma unroll
    for (int i=0;i<4;i++){
      float v = (n < FFD) ? fmaxf(acc[i][j] + bn, 0.f) : 0.f;
      z2T[n*68 + pg*4 + i] = v;
    }
  }
  __syncthreads();
  if (tid < 256) {
    int p = tid >> 2, c = tid & 3;
    if (c < 3 && (s0 + p) < NSP) {
      float a = sb3[c];
      for (int k=0;k<FFD;k++) a = fmaf(z2T[k*68 + p], sw3[c*FFD + k], a);
      zf[p*4 + c] = a;
    }
  }
  __syncthreads();
  if (tid < 64 && (s0 + tid) < NSP) {
    float z0 = zf[tid*4], z1 = zf[tid*4+1], z2 = zf[tid*4+2];
    float m = fmaxf(z0, fmaxf(z1, z2));
    float e0 = expf(z0-m), e1 = expf(z1-m), e2 = expf(z2-m);
    float inv = 1.f/(e0+e1+e2);
    int s = s0 + tid;
    sp[(b*NSP + s)*3 + 0] = e0*inv;
    sp[(b*NSP + s)*3 + 1] = e1*inv;
    sp[(b*NSP + s)*3 + 2] = e2*inv;
  }
}

// ---------------- K4: deterministic top-64 (ties -> smaller index) ----------------
__global__ __launch_bounds__(64) void k_topk(
    const float* __restrict__ sp, float* __restrict__ outT, float* __restrict__ outO,
    int* __restrict__ idxw)
{
  const int cls = blockIdx.x >> 3;   // 0: aspect(col1), 1: opinion(col2)
  const int b   = blockIdx.x & 7;
  const int lane = threadIdx.x;
  uint64_t key[10];
  #pragma unroll
  for (int q=0;q<10;q++){
    int s = lane + q*64;
    uint32_t bits = 0u;
    if (s < NSP) bits = __float_as_uint(sp[(b*NSP + s)*3 + 1 + cls]);
    key[q] = ((uint64_t)bits << 32) | (uint32_t)(1023 - s);
  }
  float* dst = cls ? outO : outT;
  for (int r = 0; r < NZK; ++r) {
    uint64_t best = key[0];
    #pragma unroll
    for (int q=1;q<10;q++) best = key[q] > best ? key[q] : best;
    #pragma unroll
    for (int off = 32; off > 0; off >>= 1) {
      uint64_t o = shfl_xor_u64(best, off);
      best = o > best ? o : best;
    }
    int sWin = 1023 - (int)(best & 0xFFFFFFFFu);
    if ((sWin & 63) == lane) {
      int qw = sWin >> 6;
      #pragma unroll
      for (int q=0;q<10;q++) if (q == qw) key[q] = 0;
    }
    if (lane == 0) {
      dst[b*NZK + r] = (float)sWin;
      idxw[cls*512 + b*NZK + r] = sWin;
    }
  }
}

// ---------------- K5a: Zt/Zo partial pair projections over selected spans ----------------
__global__ __launch_bounds__(320) void k_zto(
    const float* __restrict__ out, const float* __restrict__ wemb,
    const float* __restrict__ pw1, const int* __restrict__ idxw,
    float* __restrict__ ZTO)
{
  const int wg = blockIdx.x;
  const int cls = wg >> 5;
  const int rem = wg & 31;
  const int b = rem >> 2;
  const int i0 = (rem & 3) * 16;
  __shared__ float As[16*20];
  __shared__ __align__(16) float Wt[16*172];
  __shared__ int sI[16], sJ[16], sW[16];
  const int tid = threadIdx.x;
  if (tid < 16) {
    int S = idxw[cls*512 + b*64 + i0 + tid];
    int w, i_; span_decode(S, w, i_);
    sI[tid] = i_; sJ[tid] = i_ + w - 1; sW[tid] = w;
  }
  const int pg = tid / 20, ng = tid - (tid/20)*20;
  float acc[8] = {};
  __syncthreads();
  for (int k0 = 0; k0 < 1232; k0 += 16) {
    if (tid < 256) {
      int p = tid >> 4, kk = tid & 15;
      int k = k0 + kk;
      float v = 0.f;
      if      (k < 600)  v = out[(b*LL + sI[p])*600 + k];
      else if (k < 1200) v = out[(b*LL + sJ[p])*600 + (k - 600)];
      else if (k < 1220) v = wemb[sW[p]*20 + (k - 1200)];
      As[kk*20 + p] = v;
    }
    for (int idx = tid; idx < 16*160; idx += 320) {
      int n = idx >> 4, kk = idx & 15;
      int k = k0 + kk;
      Wt[kk*172 + n] = (n < FFD && k < 1220) ? pw1[n*2568 + cls*1220 + k] : 0.f;
    }
    __syncthreads();
    #pragma unroll
    for (int kk=0;kk<16;kk++){
      float a = As[kk*20 + pg];
      float4 w0 = *(const float4*)&Wt[kk*172 + ng*8];
      float4 w1 = *(const float4*)&Wt[kk*172 + ng*8 + 4];
      acc[0] = fmaf(a, w0.x, acc[0]);
      acc[1] = fmaf(a, w0.y, acc[1]);
      acc[2] = fmaf(a, w0.z, acc[2]);
      acc[3] = fmaf(a, w0.w, acc[3]);
      acc[4] = fmaf(a, w1.x, acc[4]);
      acc[5] = fmaf(a, w1.y, acc[5]);
      acc[6] = fmaf(a, w1.z, acc[6]);
      acc[7] = fmaf(a, w1.w, acc[7]);
    }
    __syncthreads();
  }
  #pragma unroll
  for (int j=0;j<8;j++){
    int n = ng*8 + j;
    if (n < FFD) ZTO[(cls*512 + b*64 + i0 + pg)*FFD + n] = acc[j];
  }
}

// ---------------- K5b: pair head ----------------
__global__ __launch_bounds__(320) void k_pairhead(
    const float* __restrict__ ZTO, const float* __restrict__ Zd,
    const float* __restrict__ pb1,
    const float* __restrict__ pw2, const float* __restrict__ pb2,
    const float* __restrict__ pw3, const float* __restrict__ pb3,
    const int* __restrict__ idxw,
    float* __restrict__ cp)
{
  const int b  = blockIdx.y;
  const int ti = blockIdx.x;
  __shared__ __align__(16) float z1T[160*68];
  __shared__ __align__(16) float z2T[160*68];
  __shared__ __align__(16) float Wt[16*172];
  __shared__ float zf[256];
  __shared__ int oDist[64];
  const int tid = threadIdx.x;
  const int tS = idxw[b*64 + ti];
  int wT, iT; span_decode(tS, wT, iT);
  const int aT = iT, bT = iT + wT - 1;
  if (tid < 64) {
    int oS = idxw[512 + b*64 + tid];
    int wO, iO; span_decode(oS, wO, iO);
    int d1 = bT - iO;            if (d1 < 0) d1 = -d1;
    int d2 = aT - (iO + wO - 1); if (d2 < 0) d2 = -d2;
    oDist[tid] = d1 < d2 ? d1 : d2;
  }
  __syncthreads();
  const float* ZtRow = ZTO + (b*64 + ti)*FFD;
  for (int idx = tid; idx < 64*160; idx += 320) {
    int p = idx / 160, k = idx - p*160;
    float v = 0.f;
    if (k < FFD) {
      v = ZtRow[k] + ZTO[(512 + b*64 + p)*FFD + k] + Zd[oDist[p]*FFD + k] + pb1[k];
      v = fmaxf(v, 0.f);
    }
    z1T[k*68 + p] = v;
  }
  const int pg = tid / 20, ng = tid - (tid/20)*20;
  float acc[4][8] = {};
  for (int kt = 0; kt < 10; ++kt) {
    __syncthreads();
    for (int idx = tid; idx < 16*160; idx += 320) {
      int n = idx >> 4, kk = idx & 15;
      int k = kt*16 + kk;
      Wt[kk*172 + n] = (n < FFD && k < FFD) ? pw2[n*FFD + k] : 0.f;
    }
    __syncthreads();
    #pragma unroll
    for (int kk = 0; kk < 16; ++kk) {
      float4 a4 = *(const float4*)&z1T[(kt*16+kk)*68 + pg*4];
      float4 w0 = *(const float4*)&Wt[kk*172 + ng*8];
      float4 w1 = *(const float4*)&Wt[kk*172 + ng*8 + 4];
      float a_[4] = {a4.x,a4.y,a4.z,a4.w};
      float w_[8] = {w0.x,w0.y,w0.z,w0.w,w1.x,w1.y,w1.z,w1.w};
      #pragma unroll
      for (int i=0;i<4;i++)
        #pragma unroll
        for (int j=0;j<8;j++)
          acc[i][j] = fmaf(a_[i], w_[j], acc[i][j]);
    }
  }
  __syncthreads();
  #pragma unroll
  for (int j=0;j<8;j++){
    int n = ng*8 + j;
    float bn = (n < FFD) ? pb2[n] : 0.f;
    #pragma unroll
    for (int i=0;i<4;i++){
      float v = (n < FFD) ? fmaxf(acc[i][j] + bn, 0.f) : 0.f;
      z2T[n*68 + pg*4 + i] = v;
    }
  }
  __syncthreads();
  if (tid < 256) {
    int p = tid >> 2, c = tid & 3;
    float a = pb3[c];
    for (int k=0;k<FFD;k++) a = fmaf(z2T[k*68 + p], pw3[c*FFD + k], a);
    zf[tid] = a;
  }
  __syncthreads();
  if (tid < 64) {
    float z0 = zf[tid*4], z1 = zf[tid*4+1], z2 = zf[tid*4+2], z3 = zf[tid*4+3];
    float m = fmaxf(fmaxf(z0,z1), fmaxf(z2,z3));
    float e0 = expf(z0-m), e1 = expf(z1-m), e2 = expf(z2-m), e3 = expf(z3-m);
    float inv = 1.f/(e0+e1+e2+e3);
    float4 o4 = make_float4(e0*inv, e1*inv, e2*inv, e3*inv);
    *(float4*)&cp[(size_t)((b*4096 + ti*64 + tid))*4] = o4;
  }
}

// ---------------- launch ----------------
extern "C" void kernel_launch(void* const* d_in, const int* in_sizes, int n_in,
                              void* d_out, int out_size, void* d_ws, size_t ws_size,
                              hipStream_t stream) {
  const float* x    = (const float*)d_in[0];
  const float* WihF = (const float*)d_in[1];
  const float* WhhF = (const float*)d_in[2];
  const float* bihF = (const float*)d_in[3];
  const float* bhhF = (const float*)d_in[4];
  const float* WihB = (const float*)d_in[5];
  const float* WhhB = (const float*)d_in[6];
  const float* bihB = (const float*)d_in[7];
  const float* bhhB = (const float*)d_in[8];
  const float* wemb = (const float*)d_in[9];
  const float* demb = (const float*)d_in[10];
  const float* sw1  = (const float*)d_in[11];
  const float* sb1  = (const float*)d_in[12];
  const float* sw2  = (const float*)d_in[13];
  const float* sb2  = (const float*)d_in[14];
  const float* sw3  = (const float*)d_in[15];
  const float* sb3  = (const float*)d_in[16];
  const float* pw1  = (const float*)d_in[17];
  const float* pb1  = (const float*)d_in[18];
  const float* pw2  = (const float*)d_in[19];
  const float* pb2  = (const float*)d_in[20];
  const float* pw3  = (const float*)d_in[21];
  const float* pb3  = (const float*)d_in[22];

  uint8_t* wsb = (uint8_t*)d_ws;
  unsigned int* tags = (unsigned int*)wsb;         // [2][60] stride-32 (15.4 KB)
  float* hexf  = (float*)(wsb + 16384);            // [2][2][2432] floats (38.9 KB)
  float* xg    = (float*)(wsb + 131072);           // [2][128][1200][8] = 2457600 f
  float* outh  = xg   + 2457600;                   // [8][128][600]     = 614400 f
  float* UV    = outh + 614400;                    // [1024][300]       = 307200 f
  float* wcst  = UV   + 307200;                    // [6][150]          = 900 f
  float* Zd    = wcst + 900;                       // [256][150]        = 38400 f
  float* ZTO   = Zd   + 38400;                     // [1024][150]       = 153600 f
  int*  idxw   = (int*)(ZTO + 153600);             // [2][8][64]        = 1024 i

  float* o   = (float*)d_out;
  float* spO = o;              // [8][630][3]  = 15120
  float* cpO = o + 15120;      // [8][4096][4] = 131072
  float* tO  = o + 146192;     // [8][64]
  float* oO  = o + 146704;     // [8][64]

  k_xg      <<<dim3(19,16,3), 256, 0, stream>>>(x, WihF, bihF, bhhF, WihB, bihB, bhhB, xg, tags,
                                                sw1, wemb, wcst, pw1, demb, Zd);
  k_lstm    <<<dim3(2*WPD), 320, 0, stream>>>(WhhF, WhhB, xg, hexf, tags, outh);
  k_uv      <<<dim3(32,1,2), 320, 0, stream>>>(outh, sw1, UV);
  k_spanhead<<<dim3(10,8), 320, 0, stream>>>(UV, wcst, sb1, sw2, sb2, sw3, sb3, spO);
  k_topk    <<<dim3(16),  64, 0, stream>>>(spO, tO, oO, idxw);
  k_zto     <<<dim3(64),  320, 0, stream>>>(outh, wemb, pw1, idxw, ZTO);
  k_pairhead<<<dim3(64,8), 320, 0, stream>>>(ZTO, Zd, pb1, pw2, pb2, pw3, pb3, idxw, cpO);
}

// Round 8
// 1098.160 us; speedup vs baseline: 1.3562x; 1.3369x over previous
//
#include <hip/hip_runtime.h>
#include <stdint.h>
#include <stddef.h>

// ---------------- problem constants ----------------
#define BB   8
#define LL   128
#define DD   768
#define HH   300
#define G4   1200     // 4*H
#define NSP  630      // number of spans
#define FFD  150
#define NZK  64       // top-k

// LSTM persistent-kernel geometry: 60 WGs/dir, 320 threads (5 waves),
// wave w owns h-row j0+w; 16 k-segments of 20 floats per wave.
#define WPD  60
#define JC   5

__device__ __forceinline__ float sigm(float x){ return 1.0f/(1.0f+expf(-x)); }

__device__ __forceinline__ void span_decode(int s, int& w, int& i){
  if      (s < 128){ w=1; i=s; }
  else if (s < 255){ w=2; i=s-128; }
  else if (s < 381){ w=3; i=s-255; }
  else if (s < 506){ w=4; i=s-381; }
  else             { w=5; i=s-506; }
}

__device__ __forceinline__ uint64_t shfl_xor_u64(uint64_t v, int m){
  uint32_t lo = (uint32_t)v, hi = (uint32_t)(v >> 32);
  lo = (uint32_t)__shfl_xor((int)lo, m, 64);
  hi = (uint32_t)__shfl_xor((int)hi, m, 64);
  return ((uint64_t)hi << 32) | lo;
}

// ---------------- K1: xg = Wih @ x + bih + bhh  (both dirs) + const partials ----------------
// z==0/1: GEMM, xg layout [dir][t][1200][8].  z==2: width-emb & dist-emb partials.
// Block (0,0,0) zeroes the 120 per-WG step tags (signed ints; 0xAA poison is
// negative so polls are poison-safe anyway).
__global__ __launch_bounds__(256) void k_xg(
    const float* __restrict__ x,
    const float* __restrict__ WihF, const float* __restrict__ bihF, const float* __restrict__ bhhF,
    const float* __restrict__ WihB, const float* __restrict__ bihB, const float* __restrict__ bhhB,
    float* __restrict__ xg, int* __restrict__ tags,
    const float* __restrict__ sw1, const float* __restrict__ wemb, float* __restrict__ wcst,
    const float* __restrict__ pw1, const float* __restrict__ demb, float* __restrict__ Zd)
{
  if (blockIdx.z == 2) {
    int cb = blockIdx.y*19 + blockIdx.x;
    int n = threadIdx.x;
    if (n < FFD) {
      if (cb < 6) {
        float a = 0.f;
        for (int k=0;k<20;k++) a = fmaf(sw1[n*1220 + 1200 + k], wemb[cb*20 + k], a);
        wcst[cb*FFD + n] = a;
      } else if (cb < 262) {
        int d = cb - 6;
        float a = 0.f;
        for (int k=0;k<128;k++) a = fmaf(pw1[n*2568 + 2440 + k], demb[d*128 + k], a);
        Zd[d*FFD + n] = a;
      }
    }
    return;
  }
  if (blockIdx.x==0 && blockIdx.y==0 && blockIdx.z==0) {
    for (int i = threadIdx.x; i < 2*60*32; i += 256)
      __hip_atomic_store(&tags[i], 0, __ATOMIC_RELAXED, __HIP_MEMORY_SCOPE_AGENT);
  }
  const int dir = blockIdx.z;
  const float* Wih = dir ? WihB : WihF;
  const float* bi  = dir ? bihB : bihF;
  const float* bh  = dir ? bhhB : bhhF;
  const int r0 = blockIdx.x * 64;
  const int n0 = blockIdx.y * 64;   // n = t*8 + b
  __shared__ __align__(16) float As[16*68];
  __shared__ __align__(16) float Bs[16*68];
  const int tid = threadIdx.x;
  const int rl = tid >> 2, kq = tid & 3;
  const int tx = tid & 15, ty = tid >> 4;
  float acc[4][4] = {};
  for (int k0 = 0; k0 < DD; k0 += 16) {
    float4 a4 = make_float4(0.f,0.f,0.f,0.f);
    int ra = r0 + rl;
    if (ra < G4) a4 = *(const float4*)&Wih[ra*DD + k0 + kq*4];
    As[(kq*4+0)*68 + rl] = a4.x;
    As[(kq*4+1)*68 + rl] = a4.y;
    As[(kq*4+2)*68 + rl] = a4.z;
    As[(kq*4+3)*68 + rl] = a4.w;
    int n = n0 + rl; int tt = n >> 3, bb = n & 7;
    float4 b4 = *(const float4*)&x[(bb*LL + tt)*DD + k0 + kq*4];
    Bs[(kq*4+0)*68 + rl] = b4.x;
    Bs[(kq*4+1)*68 + rl] = b4.y;
    Bs[(kq*4+2)*68 + rl] = b4.z;
    Bs[(kq*4+3)*68 + rl] = b4.w;
    __syncthreads();
    #pragma unroll
    for (int kk = 0; kk < 16; ++kk) {
      float4 av = *(const float4*)&As[kk*68 + tx*4];
      float4 bv = *(const float4*)&Bs[kk*68 + ty*4];
      float a_[4] = {av.x,av.y,av.z,av.w};
      float b_[4] = {bv.x,bv.y,bv.z,bv.w};
      #pragma unroll
      for (int i=0;i<4;i++)
        #pragma unroll
        for (int j=0;j<4;j++)
          acc[i][j] = fmaf(a_[i], b_[j], acc[i][j]);
    }
    __syncthreads();
  }
  #pragma unroll
  for (int i=0;i<4;i++){
    int r = r0 + tx*4 + i;
    if (r >= G4) continue;
    float bias = bi[r] + bh[r];
    #pragma unroll
    for (int j=0;j<4;j++){
      int n = n0 + ty*4 + j; int tt = n>>3, bb = n&7;
      xg[((dir*LL + tt)*G4 + r)*8 + bb] = acc[i][j] + bias;
    }
  }
}

// ---------------- K2: persistent bidirectional LSTM (R5 protocol, verbatim) ----------------
// 120 wg (60/dir), 320 thr. Wave w owns h-row j = wid*5+w; Whh slice in regs.
// Readiness: per-producer tag line (posted by tid0 AFTER __syncthreads, whose
// vmcnt(0) drain orders it behind the h stores). Wave0 polls 60 tags,
// relays via LDS flag. Data: one-shot bulk read of the h block with
// global_load_dwordx4 sc0 sc1 (MALL-coherent). hex parity double-buffered.
// NEW: runs steps [t0,t1) so the 128-step loop can be split into multiple
// dispatches; cell state handed off via cstash; h/tags persist in ws.
__global__ __launch_bounds__(320) void k_lstm(
    const float* __restrict__ WhhF, const float* __restrict__ WhhB,
    const float* __restrict__ xg,
    float* __restrict__ hexf,           // [2 parity][2 dir][8][304] floats
    int* __restrict__ tags,             // [2][60] stride-32 ints
    float* __restrict__ out,            // [b][t][600]
    float* __restrict__ cstash,         // [120][5][8] cell-state handoff
    int t0, int t1)
{
  const int wg  = blockIdx.x;
  const int dir = wg / WPD;
  const int wid = wg - dir*WPD;
  const int j0  = wid * JC;
  const float* Whh = dir ? WhhB : WhhF;
  float* hex0 = hexf + (size_t)dir*2432;       // parity 0 base
  int* tg = tags + dir*60*32;

  __shared__ __align__(16) float hls[8*304 + 16];
  __shared__ int hready;

  const int tid  = threadIdx.x;   // 0..319
  const int wv   = tid >> 6;      // wave id = local j
  const int lane = tid & 63;
  const int rl   = lane >> 4;     // gate 0..3
  const int s    = lane & 15;     // k-segment (20 floats)
  const int jj   = j0 + wv;
  const int Rabs = rl*HH + jj;
  const int bb   = s & 7;

  // register-resident Whh slice: 20 floats (5 float4) per thread
  float4 w4[5];
  #pragma unroll
  for (int q=0;q<5;q++){
    int k = s*20 + q*4;
    if (k + 3 < HH) w4[q] = *(const float4*)&Whh[(size_t)Rabs*HH + k];
    else            w4[q] = make_float4(0.f,0.f,0.f,0.f);
  }
  float creg = 0.f;               // cell state, valid on lanes<8 (b=lane)
  if (t0 > 0 && lane < 8)
    creg = cstash[((size_t)wg*JC + wv)*8 + lane];
  if (tid == 0) hready = 0;
  {
    float4* h4 = (float4*)hls;    // zeros (incl. pads)
    for (int i = tid; i < 612; i += 320) h4[i] = make_float4(0.f,0.f,0.f,0.f);
  }
  __syncthreads();

  float xg_c = xg[((size_t)(dir*LL + (dir ? LL-1 - t0 : t0))*G4 + Rabs)*8 + bb];

  for (int t = t0; t < t1; ++t) {
    const int tOrig = dir ? (LL-1 - t) : t;
    // prefetch next step's xg (overlaps poll/read latency)
    float xg_n = 0.f;
    if (t+1 < t1) {
      int tO2 = dir ? (LL-2 - t) : (t+1);
      xg_n = xg[((size_t)(dir*LL + tO2)*G4 + Rabs)*8 + bb];
    }
    if (t > 0) {
      // readiness: wave0 polls 60 tag lines; others spin on LDS flag
      if (wv == 0) {
        if (lane < 60) {
          while (__hip_atomic_load(&tg[lane*32], __ATOMIC_RELAXED,
                                   __HIP_MEMORY_SCOPE_AGENT) < t)
            __builtin_amdgcn_s_sleep(1);
        }
        if (lane == 0) ((volatile int*)&hready)[0] = t;
      } else {
        while (((volatile int*)&hready)[0] < t) __builtin_amdgcn_s_sleep(1);
      }
      // one-shot bulk read from parity t&1: 608 float4, MALL-coherent
      if (tid < 304) {
        const float* p0 = hex0 + (size_t)(t&1)*4864 + tid*8;
        float4 v0, v1;
        asm volatile(
          "global_load_dwordx4 %0, %2, off sc0 sc1\n\t"
          "global_load_dwordx4 %1, %3, off sc0 sc1\n\t"
          "s_waitcnt vmcnt(0)"
          : "=v"(v0), "=v"(v1)
          : "v"(p0), "v"(p0 + 4)
          : "memory");
        float4* d = (float4*)&hls[tid*8];
        d[0] = v0; d[1] = v1;
      }
    }
    __syncthreads();                          // B1: hls ready
    // partial dot products (4 gate rows/wave broadcast-share each LDS word)
    float p[8];
    {
      const float4* h4 = (const float4*)hls;
      #pragma unroll
      for (int b=0;b<8;b++){
        const float4* hb = h4 + b*76 + s*5;   // 304 floats = 76 f4 per row
        float ax=0.f, ay=0.f, az=0.f, aw=0.f;
        #pragma unroll
        for (int q=0;q<5;q++){
          float4 hv = hb[q];
          ax = fmaf(w4[q].x, hv.x, ax);
          ay = fmaf(w4[q].y, hv.y, ay);
          az = fmaf(w4[q].z, hv.z, az);
          aw = fmaf(w4[q].w, hv.w, aw);
        }
        p[b] = (ax+ay)+(az+aw);
      }
    }
    // butterfly reduce-scatter over the 16 s-lanes
    #pragma unroll
    for (int b=0;b<8;b++) p[b] += __shfl_xor(p[b], 8, 64);
    float q4[4];
    #pragma unroll
    for (int b=0;b<4;b++){
      float mine = (s&4) ? p[b+4] : p[b];
      float oth  = (s&4) ? p[b]   : p[b+4];
      q4[b] = mine + __shfl_xor(oth, 4, 64);
    }
    float q2[2];
    #pragma unroll
    for (int b=0;b<2;b++){
      float mine = (s&2) ? q4[b+2] : q4[b];
      float oth  = (s&2) ? q4[b]   : q4[b+2];
      q2[b] = mine + __shfl_xor(oth, 2, 64);
    }
    float gv;
    {
      float mine = (s&1) ? q2[1] : q2[0];
      float oth  = (s&1) ? q2[0] : q2[1];
      gv = mine + __shfl_xor(oth, 1, 64) + xg_c;  // valid on s<8 (b=s)
    }
    // gather the 4 gates of (j=jj, b) in-wave
    {
      int bsel = lane & 7;
      float g_i = __shfl(gv,      bsel, 64);
      float g_f = __shfl(gv, 16 + bsel, 64);
      float g_g = __shfl(gv, 32 + bsel, 64);
      float g_o = __shfl(gv, 48 + bsel, 64);
      if (lane < 8) {
        int b = lane;
        float ig = sigm(g_i), fg = sigm(g_f), gg = tanhf(g_g), og = sigm(g_o);
        creg = fg * creg + ig * gg;
        float h = og * tanhf(creg);
        out[((size_t)(b*LL + tOrig))*600 + dir*HH + jj] = h;
        if (t+1 < LL)
          __hip_atomic_store(&hex0[(size_t)(((t+1)&1))*4864 + b*304 + jj], h,
                             __ATOMIC_RELAXED, __HIP_MEMORY_SCOPE_AGENT);
      }
    }
    __syncthreads();   // B2: drains vmcnt(0) -> h stores visible
    if (t+1 < LL && tid == 0)
      __hip_atomic_store(&tg[wid*32], t+1,
                         __ATOMIC_RELAXED, __HIP_MEMORY_SCOPE_AGENT);
    xg_c = xg_n;
  }
  if (t1 < LL && lane < 8)
    cstash[((size_t)wg*JC + wv)*8 + lane] = creg;
}

// ---------------- K3a: U/V partial span projections (16 rows/block) ----------------
// UV[row][half*150+n] = sum_k sw1[n][half*600+k] * out[row][k],  row = b*128+l
__global__ __launch_bounds__(320) void k_uv(
    const float* __restrict__ out, const float* __restrict__ sw1, float* __restrict__ UV)
{
  const int half = blockIdx.z;
  const int row0 = blockIdx.x * 16;
  __shared__ float As[16*20];
  __shared__ __align__(16) float Wt[16*172];
  const int tid = threadIdx.x;
  const int pg = tid / 20, ng = tid - (tid/20)*20;
  float acc[8] = {};
  for (int k0 = 0; k0 < 600; k0 += 16) {
    if (tid < 256) {
      int p = tid >> 4, kk = tid & 15;
      int k = k0 + kk;
      As[kk*20 + p] = (k < 600) ? out[(row0 + p)*600 + k] : 0.f;
    }
    for (int idx = tid; idx < 16*160; idx += 320) {
      int n = idx >> 4, kk = idx & 15;
      int k = k0 + kk;
      Wt[kk*172 + n] = (n < FFD && k < 600) ? sw1[n*1220 + half*600 + k] : 0.f;
    }
    __syncthreads();
    #pragma unroll
    for (int kk=0;kk<16;kk++){
      float a = As[kk*20 + pg];
      float4 w0 = *(const float4*)&Wt[kk*172 + ng*8];
      float4 w1 = *(const float4*)&Wt[kk*172 + ng*8 + 4];
      acc[0] = fmaf(a, w0.x, acc[0]);
      acc[1] = fmaf(a, w0.y, acc[1]);
      acc[2] = fmaf(a, w0.z, acc[2]);
      acc[3] = fmaf(a, w0.w, acc[3]);
      acc[4] = fmaf(a, w1.x, acc[4]);
      acc[5] = fmaf(a, w1.y, acc[5]);
      acc[6] = fmaf(a, w1.z, acc[6]);
      acc[7] = fmaf(a, w1.w, acc[7]);
    }
    __syncthreads();
  }
  {
    int row = row0 + pg;
    #pragma unroll
    for (int j=0;j<8;j++){
      int n = ng*8 + j;
      if (n < FFD) UV[row*300 + half*FFD + n] = acc[j];
    }
  }
}

// ---------------- K3b: span head, 32 spans/block ----------------
__global__ __launch_bounds__(320) void k_spanhead(
    const float* __restrict__ UV, const float* __restrict__ wcst,
    const float* __restrict__ sb1,
    const float* __restrict__ sw2, const float* __restrict__ sb2,
    const float* __restrict__ sw3, const float* __restrict__ sb3,
    float* __restrict__ sp)
{
  const int b  = blockIdx.y;
  const int s0 = blockIdx.x * 32;
  __shared__ __align__(16) float z1T[160*36];
  __shared__ __align__(16) float z2T[160*36];
  __shared__ __align__(16) float Wt[16*172];
  __shared__ float zf[128];
  __shared__ int sI[32], sJ[32], sW[32];
  const int tid = threadIdx.x;
  if (tid < 32) {
    int s = s0 + tid; int w = 1, i0 = 0;
    if (s < NSP) span_decode(s, w, i0);
    sI[tid] = i0; sJ[tid] = i0 + w - 1; sW[tid] = w;
  }
  __syncthreads();
  for (int idx = tid; idx < 32*160; idx += 320) {
    int p = idx / 160, k = idx - p*160;
    float v = 0.f;
    if (k < FFD && (s0 + p) < NSP) {
      v = UV[(b*LL + sI[p])*300 + k] + UV[(b*LL + sJ[p])*300 + FFD + k]
        + wcst[sW[p]*FFD + k] + sb1[k];
      v = fmaxf(v, 0.f);
    }
    z1T[k*36 + p] = v;
  }
  const int pg = tid / 20, ng = tid - (tid/20)*20;
  float acc[2][8] = {};
  for (int kt = 0; kt < 10; ++kt) {
    __syncthreads();
    for (int idx = tid; idx < 16*160; idx += 320) {
      int n = idx >> 4, kk = idx & 15;
      int k = kt*16 + kk;
      Wt[kk*172 + n] = (n < FFD && k < FFD) ? sw2[n*FFD + k] : 0.f;
    }
    __syncthreads();
    #pragma unroll
    for (int kk = 0; kk < 16; ++kk) {
      float2 a2 = *(const float2*)&z1T[(kt*16+kk)*36 + pg*2];
      float4 w0 = *(const float4*)&Wt[kk*172 + ng*8];
      float4 w1 = *(const float4*)&Wt[kk*172 + ng*8 + 4];
      float a_[2] = {a2.x, a2.y};
      float w_[8] = {w0.x,w0.y,w0.z,w0.w,w1.x,w1.y,w1.z,w1.w};
      #pragma unroll
      for (int i=0;i<2;i++)
        #pragma unroll
        for (int j=0;j<8;j++)
          acc[i][j] = fmaf(a_[i], w_[j], acc[i][j]);
    }
  }
  __syncthreads();
  #pragma unroll
  for (int j=0;j<8;j++){
    int n = ng*8 + j;
    float bn = (n < FFD) ? sb2[n] : 0.f;
    #pragma unroll
    for (int i=0;i<2;i++){
      float v = (n < FFD) ? fmaxf(acc[i][j] + bn, 0.f) : 0.f;
      z2T[n*36 + pg*2 + i] = v;
    }
  }
  __syncthreads();
  if (tid < 128) {
    int p = tid >> 2, c = tid & 3;
    if (c < 3 && (s0 + p) < NSP) {
      float a = sb3[c];
      for (int k=0;k<FFD;k++) a = fmaf(z2T[k*36 + p], sw3[c*FFD + k], a);
      zf[p*4 + c] = a;
    }
  }
  __syncthreads();
  if (tid < 32 && (s0 + tid) < NSP) {
    float z0 = zf[tid*4], z1 = zf[tid*4+1], z2 = zf[tid*4+2];
    float m = fmaxf(z0, fmaxf(z1, z2));
    float e0 = expf(z0-m), e1 = expf(z1-m), e2 = expf(z2-m);
    float inv = 1.f/(e0+e1+e2);
    int s = s0 + tid;
    sp[(b*NSP + s)*3 + 0] = e0*inv;
    sp[(b*NSP + s)*3 + 1] = e1*inv;
    sp[(b*NSP + s)*3 + 2] = e2*inv;
  }
}

// ---------------- K4: deterministic top-64 (ties -> smaller index) ----------------
__global__ __launch_bounds__(64) void k_topk(
    const float* __restrict__ sp, float* __restrict__ outT, float* __restrict__ outO,
    int* __restrict__ idxw)
{
  const int cls = blockIdx.x >> 3;   // 0: aspect(col1), 1: opinion(col2)
  const int b   = blockIdx.x & 7;
  const int lane = threadIdx.x;
  uint64_t key[10];
  #pragma unroll
  for (int q=0;q<10;q++){
    int s = lane + q*64;
    uint32_t bits = 0u;
    if (s < NSP) bits = __float_as_uint(sp[(b*NSP + s)*3 + 1 + cls]);
    key[q] = ((uint64_t)bits << 32) | (uint32_t)(1023 - s);
  }
  float* dst = cls ? outO : outT;
  for (int r = 0; r < NZK; ++r) {
    uint64_t best = key[0];
    #pragma unroll
    for (int q=1;q<10;q++) best = key[q] > best ? key[q] : best;
    #pragma unroll
    for (int off = 32; off > 0; off >>= 1) {
      uint64_t o = shfl_xor_u64(best, off);
      best = o > best ? o : best;
    }
    int sWin = 1023 - (int)(best & 0xFFFFFFFFu);
    if ((sWin & 63) == lane) {
      int qw = sWin >> 6;
      #pragma unroll
      for (int q=0;q<10;q++) if (q == qw) key[q] = 0;
    }
    if (lane == 0) {
      dst[b*NZK + r] = (float)sWin;
      idxw[cls*512 + b*NZK + r] = sWin;
    }
  }
}

// ---------------- K5a: Zt/Zo partial pair projections, K-split x2 ----------------
// grid 128: kh = bx>>6 selects K-range half; partial sums to ZTO[kh][slot][150].
__global__ __launch_bounds__(320) void k_zto(
    const float* __restrict__ out, const float* __restrict__ wemb,
    const float* __restrict__ pw1, const int* __restrict__ idxw,
    float* __restrict__ ZTO)
{
  const int kh  = blockIdx.x >> 6;
  const int r6  = blockIdx.x & 63;
  const int cls = r6 >> 5;
  const int rem = r6 & 31;
  const int b = rem >> 2;
  const int i0 = (rem & 3) * 16;
  const int kbeg = kh ? 640 : 0;
  const int kend = kh ? 1232 : 640;
  __shared__ float As[16*20];
  __shared__ __align__(16) float Wt[16*172];
  __shared__ int sI[16], sJ[16], sW[16];
  const int tid = threadIdx.x;
  if (tid < 16) {
    int S = idxw[cls*512 + b*64 + i0 + tid];
    int w, i_; span_decode(S, w, i_);
    sI[tid] = i_; sJ[tid] = i_ + w - 1; sW[tid] = w;
  }
  const int pg = tid / 20, ng = tid - (tid/20)*20;
  float acc[8] = {};
  __syncthreads();
  for (int k0 = kbeg; k0 < kend; k0 += 16) {
    if (tid < 256) {
      int p = tid >> 4, kk = tid & 15;
      int k = k0 + kk;
      float v = 0.f;
      if      (k < 600)  v = out[(b*LL + sI[p])*600 + k];
      else if (k < 1200) v = out[(b*LL + sJ[p])*600 + (k - 600)];
      else if (k < 1220) v = wemb[sW[p]*20 + (k - 1200)];
      As[kk*20 + p] = v;
    }
    for (int idx = tid; idx < 16*160; idx += 320) {
      int n = idx >> 4, kk = idx & 15;
      int k = k0 + kk;
      Wt[kk*172 + n] = (n < FFD && k < 1220) ? pw1[n*2568 + cls*1220 + k] : 0.f;
    }
    __syncthreads();
    #pragma unroll
    for (int kk=0;kk<16;kk++){
      float a = As[kk*20 + pg];
      float4 w0 = *(const float4*)&Wt[kk*172 + ng*8];
      float4 w1 = *(const float4*)&Wt[kk*172 + ng*8 + 4];
      acc[0] = fmaf(a, w0.x, acc[0]);
      acc[1] = fmaf(a, w0.y, acc[1]);
      acc[2] = fmaf(a, w0.z, acc[2]);
      acc[3] = fmaf(a, w0.w, acc[3]);
      acc[4] = fmaf(a, w1.x, acc[4]);
      acc[5] = fmaf(a, w1.y, acc[5]);
      acc[6] = fmaf(a, w1.z, acc[6]);
      acc[7] = fmaf(a, w1.w, acc[7]);
    }
    __syncthreads();
  }
  #pragma unroll
  for (int j=0;j<8;j++){
    int n = ng*8 + j;
    if (n < FFD) ZTO[(size_t)kh*153600 + (cls*512 + b*64 + i0 + pg)*FFD + n] = acc[j];
  }
}

// ---------------- K5b: pair head (sums both ZTO K-halves) ----------------
__global__ __launch_bounds__(320) void k_pairhead(
    const float* __restrict__ ZTO, const float* __restrict__ Zd,
    const float* __restrict__ pb1,
    const float* __restrict__ pw2, const float* __restrict__ pb2,
    const float* __restrict__ pw3, const float* __restrict__ pb3,
    const int* __restrict__ idxw,
    float* __restrict__ cp)
{
  const int b  = blockIdx.y;
  const int ti = blockIdx.x;
  __shared__ __align__(16) float z1T[160*68];
  __shared__ __align__(16) float z2T[160*68];
  __shared__ __align__(16) float Wt[16*172];
  __shared__ float zf[256];
  __shared__ int oDist[64];
  const int tid = threadIdx.x;
  const int tS = idxw[b*64 + ti];
  int wT, iT; span_decode(tS, wT, iT);
  const int aT = iT, bT = iT + wT - 1;
  if (tid < 64) {
    int oS = idxw[512 + b*64 + tid];
    int wO, iO; span_decode(oS, wO, iO);
    int d1 = bT - iO;            if (d1 < 0) d1 = -d1;
    int d2 = aT - (iO + wO - 1); if (d2 < 0) d2 = -d2;
    oDist[tid] = d1 < d2 ? d1 : d2;
  }
  __syncthreads();
  const float* Zt0 = ZTO + (b*64 + ti)*FFD;
  const float* Zt1 = Zt0 + 153600;
  for (int idx = tid; idx < 64*160; idx += 320) {
    int p = idx / 160, k = idx - p*160;
    float v = 0.f;
    if (k < FFD) {
      int os = (512 + b*64 + p)*FFD + k;
      v = Zt0[k] + Zt1[k] + ZTO[os] + ZTO[153600 + os] + Zd[oDist[p]*FFD + k] + pb1[k];
      v = fmaxf(v, 0.f);
    }
    z1T[k*68 + p] = v;
  }
  const int pg = tid / 20, ng = tid - (tid/20)*20;
  float acc[4][8] = {};
  for (int kt = 0; kt < 10; ++kt) {
    __syncthreads();
    for (int idx = tid; idx < 16*160; idx += 320) {
      int n = idx >> 4, kk = idx & 15;
      int k = kt*16 + kk;
      Wt[kk*172 + n] = (n < FFD && k < FFD) ? pw2[n*FFD + k] : 0.f;
    }
    __syncthreads();
    #pragma unroll
    for (int kk = 0; kk < 16; ++kk) {
      float4 a4 = *(const float4*)&z1T[(kt*16+kk)*68 + pg*4];
      float4 w0 = *(const float4*)&Wt[kk*172 + ng*8];
      float4 w1 = *(const float4*)&Wt[kk*172 + ng*8 + 4];
      float a_[4] = {a4.x,a4.y,a4.z,a4.w};
      float w_[8] = {w0.x,w0.y,w0.z,w0.w,w1.x,w1.y,w1.z,w1.w};
      #pragma unroll
      for (int i=0;i<4;i++)
        #pragma unroll
        for (int j=0;j<8;j++)
          acc[i][j] = fmaf(a_[i], w_[j], acc[i][j]);
    }
  }
  __syncthreads();
  #pragma unroll
  for (int j=0;j<8;j++){
    int n = ng*8 + j;
    float bn = (n < FFD) ? pb2[n] : 0.f;
    #pragma unroll
    for (int i=0;i<4;i++){
      float v = (n < FFD) ? fmaxf(acc[i][j] + bn, 0.f) : 0.f;
      z2T[n*68 + pg*4 + i] = v;
    }
  }
  __syncthreads();
  if (tid < 256) {
    int p = tid >> 2, c = tid & 3;
    float a = pb3[c];
    for (int k=0;k<FFD;k++) a = fmaf(z2T[k*68 + p], pw3[c*FFD + k], a);
    zf[tid] = a;
  }
  __syncthreads();
  if (tid < 64) {
    float z0 = zf[tid*4], z1 = zf[tid*4+1], z2 = zf[tid*4+2], z3 = zf[tid*4+3];
    float m = fmaxf(fmaxf(z0,z1), fmaxf(z2,z3));
    float e0 = expf(z0-m), e1 = expf(z1-m), e2 = expf(z2-m), e3 = expf(z3-m);
    float inv = 1.f/(e0+e1+e2+e3);
    float4 o4 = make_float4(e0*inv, e1*inv, e2*inv, e3*inv);
    *(float4*)&cp[(size_t)((b*4096 + ti*64 + tid))*4] = o4;
  }
}

// ---------------- launch ----------------
extern "C" void kernel_launch(void* const* d_in, const int* in_sizes, int n_in,
                              void* d_out, int out_size, void* d_ws, size_t ws_size,
                              hipStream_t stream) {
  const float* x    = (const float*)d_in[0];
  const float* WihF = (const float*)d_in[1];
  const float* WhhF = (const float*)d_in[2];
  const float* bihF = (const float*)d_in[3];
  const float* bhhF = (const float*)d_in[4];
  const float* WihB = (const float*)d_in[5];
  const float* WhhB = (const float*)d_in[6];
  const float* bihB = (const float*)d_in[7];
  const float* bhhB = (const float*)d_in[8];
  const float* wemb = (const float*)d_in[9];
  const float* demb = (const float*)d_in[10];
  const float* sw1  = (const float*)d_in[11];
  const float* sb1  = (const float*)d_in[12];
  const float* sw2  = (const float*)d_in[13];
  const float* sb2  = (const float*)d_in[14];
  const float* sw3  = (const float*)d_in[15];
  const float* sb3  = (const float*)d_in[16];
  const float* pw1  = (const float*)d_in[17];
  const float* pb1  = (const float*)d_in[18];
  const float* pw2  = (const float*)d_in[19];
  const float* pb2  = (const float*)d_in[20];
  const float* pw3  = (const float*)d_in[21];
  const float* pb3  = (const float*)d_in[22];

  uint8_t* wsb = (uint8_t*)d_ws;
  int*   tags  = (int*)wsb;                        // [2][60] stride-32 (15.4 KB)
  float* hexf  = (float*)(wsb + 16384);            // [2][2][8][304] floats (38.9 KB)
  float* cstash= (float*)(wsb + 57344);            // [120][5][8] = 4800 f (19.2 KB)
  float* xg    = (float*)(wsb + 131072);           // [2][128][1200][8] = 2457600 f
  float* outh  = xg   + 2457600;                   // [8][128][600]     = 614400 f
  float* UV    = outh + 614400;                    // [1024][300]       = 307200 f
  float* wcst  = UV   + 307200;                    // [6][150]          = 900 f
  float* Zd    = wcst + 900;                       // [256][150]        = 38400 f
  float* ZTO   = Zd   + 38400;                     // [2][1024][150]    = 307200 f
  int*  idxw   = (int*)(ZTO + 307200);             // [2][8][64]        = 1024 i

  float* o   = (float*)d_out;
  float* spO = o;              // [8][630][3]  = 15120
  float* cpO = o + 15120;      // [8][4096][4] = 131072
  float* tO  = o + 146192;     // [8][64]
  float* oO  = o + 146704;     // [8][64]

  k_xg      <<<dim3(19,16,3), 256, 0, stream>>>(x, WihF, bihF, bhhF, WihB, bihB, bhhB, xg, tags,
                                                sw1, wemb, wcst, pw1, demb, Zd);
  k_lstm    <<<dim3(2*WPD), 320, 0, stream>>>(WhhF, WhhB, xg, hexf, tags, outh, cstash, 0, 64);
  k_lstm    <<<dim3(2*WPD), 320, 0, stream>>>(WhhF, WhhB, xg, hexf, tags, outh, cstash, 64, 128);
  k_uv      <<<dim3(64,1,2), 320, 0, stream>>>(outh, sw1, UV);
  k_spanhead<<<dim3(20,8), 320, 0, stream>>>(UV, wcst, sb1, sw2, sb2, sw3, sb3, spO);
  k_topk    <<<dim3(16),  64, 0, stream>>>(spO, tO, oO, idxw);
  k_zto     <<<dim3(128), 320, 0, stream>>>(outh, wemb, pw1, idxw, ZTO);
  k_pairhead<<<dim3(64,8), 320, 0, stream>>>(ZTO, Zd, pb1, pw2, pb2, pw3, pb3, idxw, cpO);
}

// Round 11
// 1004.039 us; speedup vs baseline: 1.4834x; 1.0937x over previous
//
#include <hip/hip_runtime.h>
#include <stdint.h>
#include <stddef.h>

// ---------------- problem constants ----------------
#define BB   8
#define LL   128
#define DD   768
#define HH   300
#define G4   1200     // 4*H
#define NSP  630      // number of spans
#define FFD  150
#define NZK  64       // top-k

// LSTM persistent-kernel geometry: 60 WGs/dir, 320 threads (5 waves),
// wave w owns h-row j0+w; 16 k-segments of 20 floats per wave.
#define WPD  60
#define JC   5

__device__ __forceinline__ float sigm(float x){ return 1.0f/(1.0f+expf(-x)); }

__device__ __forceinline__ void span_decode(int s, int& w, int& i){
  if      (s < 128){ w=1; i=s; }
  else if (s < 255){ w=2; i=s-128; }
  else if (s < 381){ w=3; i=s-255; }
  else if (s < 506){ w=4; i=s-381; }
  else             { w=5; i=s-506; }
}

__device__ __forceinline__ uint64_t shfl_xor_u64(uint64_t v, int m){
  uint32_t lo = (uint32_t)v, hi = (uint32_t)(v >> 32);
  lo = (uint32_t)__shfl_xor((int)lo, m, 64);
  hi = (uint32_t)__shfl_xor((int)hi, m, 64);
  return ((uint64_t)hi << 32) | lo;
}

// ---------------- K1: xg = Wih @ x + bih + bhh  (both dirs) + const partials ----------------
// R8-verbatim (NON-prefetched; the R9/R10 prefetch rewrite correlated with
// replay-phase correctness failures and is banned).
// z==0/1: GEMM, xg layout [dir][t][1200][8].  z==2: width-emb & dist-emb partials.
__global__ __launch_bounds__(256) void k_xg(
    const float* __restrict__ x,
    const float* __restrict__ WihF, const float* __restrict__ bihF, const float* __restrict__ bhhF,
    const float* __restrict__ WihB, const float* __restrict__ bihB, const float* __restrict__ bhhB,
    float* __restrict__ xg, int* __restrict__ tags,
    const float* __restrict__ sw1, const float* __restrict__ wemb, float* __restrict__ wcst,
    const float* __restrict__ pw1, const float* __restrict__ demb, float* __restrict__ Zd)
{
  if (blockIdx.z == 2) {
    int cb = blockIdx.y*19 + blockIdx.x;
    int n = threadIdx.x;
    if (n < FFD) {
      if (cb < 6) {
        float a = 0.f;
        for (int k=0;k<20;k++) a = fmaf(sw1[n*1220 + 1200 + k], wemb[cb*20 + k], a);
        wcst[cb*FFD + n] = a;
      } else if (cb < 262) {
        int d = cb - 6;
        float a = 0.f;
        for (int k=0;k<128;k++) a = fmaf(pw1[n*2568 + 2440 + k], demb[d*128 + k], a);
        Zd[d*FFD + n] = a;
      }
    }
    return;
  }
  if (blockIdx.x==0 && blockIdx.y==0 && blockIdx.z==0) {
    for (int i = threadIdx.x; i < 2*60*32; i += 256)
      __hip_atomic_store(&tags[i], 0, __ATOMIC_RELAXED, __HIP_MEMORY_SCOPE_AGENT);
  }
  const int dir = blockIdx.z;
  const float* Wih = dir ? WihB : WihF;
  const float* bi  = dir ? bihB : bihF;
  const float* bh  = dir ? bhhB : bhhF;
  const int r0 = blockIdx.x * 64;
  const int n0 = blockIdx.y * 64;   // n = t*8 + b
  __shared__ __align__(16) float As[16*68];
  __shared__ __align__(16) float Bs[16*68];
  const int tid = threadIdx.x;
  const int rl = tid >> 2, kq = tid & 3;
  const int tx = tid & 15, ty = tid >> 4;
  float acc[4][4] = {};
  for (int k0 = 0; k0 < DD; k0 += 16) {
    float4 a4 = make_float4(0.f,0.f,0.f,0.f);
    int ra = r0 + rl;
    if (ra < G4) a4 = *(const float4*)&Wih[ra*DD + k0 + kq*4];
    As[(kq*4+0)*68 + rl] = a4.x;
    As[(kq*4+1)*68 + rl] = a4.y;
    As[(kq*4+2)*68 + rl] = a4.z;
    As[(kq*4+3)*68 + rl] = a4.w;
    int n = n0 + rl; int tt = n >> 3, bb = n & 7;
    float4 b4 = *(const float4*)&x[(bb*LL + tt)*DD + k0 + kq*4];
    Bs[(kq*4+0)*68 + rl] = b4.x;
    Bs[(kq*4+1)*68 + rl] = b4.y;
    Bs[(kq*4+2)*68 + rl] = b4.z;
    Bs[(kq*4+3)*68 + rl] = b4.w;
    __syncthreads();
    #pragma unroll
    for (int kk = 0; kk < 16; ++kk) {
      float4 av = *(const float4*)&As[kk*68 + tx*4];
      float4 bv = *(const float4*)&Bs[kk*68 + ty*4];
      float a_[4] = {av.x,av.y,av.z,av.w};
      float b_[4] = {bv.x,bv.y,bv.z,bv.w};
      #pragma unroll
      for (int i=0;i<4;i++)
        #pragma unroll
        for (int j=0;j<4;j++)
          acc[i][j] = fmaf(a_[i], b_[j], acc[i][j]);
    }
    __syncthreads();
  }
  #pragma unroll
  for (int i=0;i<4;i++){
    int r = r0 + tx*4 + i;
    if (r >= G4) continue;
    float bias = bi[r] + bh[r];
    #pragma unroll
    for (int j=0;j<4;j++){
      int n = n0 + ty*4 + j; int tt = n>>3, bb = n&7;
      xg[((dir*LL + tt)*G4 + r)*8 + bb] = acc[i][j] + bias;
    }
  }
}

// ---------------- K2: persistent bidirectional LSTM (Round-5 VERBATIM, merged 0..128) ----------------
// 120 wg (60/dir), 320 thr. Wave w owns h-row j = wid*5+w; Whh slice in regs.
// Readiness: per-producer tag line posted by tid0 AFTER __syncthreads (whose
// vmcnt(0) drain orders it behind BOTH the out and hex stores). Wave0 polls
// 60 tags, relays via LDS flag. Data: one-shot bulk dwordx4 sc0 sc1 read;
// hex parity double-buffered. Store order out -> hex -> B2 -> tag is the
// validated configuration (R5/R8); do not reorder.
__global__ __launch_bounds__(320) void k_lstm(
    const float* __restrict__ WhhF, const float* __restrict__ WhhB,
    const float* __restrict__ xg,
    float* __restrict__ hexf,           // [2 parity][2 dir][8][304] floats
    int* __restrict__ tags,             // [2][60] stride-32 ints
    float* __restrict__ out)            // [b][t][600]
{
  const int wg  = blockIdx.x;
  const int dir = wg / WPD;
  const int wid = wg - dir*WPD;
  const int j0  = wid * JC;
  const float* Whh = dir ? WhhB : WhhF;
  float* hex0 = hexf + (size_t)dir*2432;       // parity 0 base
  int* tg = tags + dir*60*32;

  __shared__ __align__(16) float hls[8*304 + 16];
  __shared__ int hready;

  const int tid  = threadIdx.x;   // 0..319
  const int wv   = tid >> 6;      // wave id = local j
  const int lane = tid & 63;
  const int rl   = lane >> 4;     // gate 0..3
  const int s    = lane & 15;     // k-segment (20 floats)
  const int jj   = j0 + wv;
  const int Rabs = rl*HH + jj;
  const int bb   = s & 7;

  // register-resident Whh slice: 20 floats (5 float4) per thread
  float4 w4[5];
  #pragma unroll
  for (int q=0;q<5;q++){
    int k = s*20 + q*4;
    if (k + 3 < HH) w4[q] = *(const float4*)&Whh[(size_t)Rabs*HH + k];
    else            w4[q] = make_float4(0.f,0.f,0.f,0.f);
  }
  float creg = 0.f;               // cell state, valid on lanes<8 (b=lane)
  if (tid == 0) hready = 0;
  {
    float4* h4 = (float4*)hls;    // zeros (incl. pads)
    for (int i = tid; i < 612; i += 320) h4[i] = make_float4(0.f,0.f,0.f,0.f);
  }
  __syncthreads();

  float xg_c = xg[((size_t)(dir*LL + (dir ? LL-1 : 0))*G4 + Rabs)*8 + bb];

  for (int t = 0; t < LL; ++t) {
    const int tOrig = dir ? (LL-1 - t) : t;
    // prefetch next step's xg (overlaps poll/read latency)
    float xg_n = 0.f;
    if (t+1 < LL) {
      int tO2 = dir ? (LL-2 - t) : (t+1);
      xg_n = xg[((size_t)(dir*LL + tO2)*G4 + Rabs)*8 + bb];
    }
    if (t > 0) {
      // readiness: wave0 polls 60 tag lines; others spin on LDS flag
      if (wv == 0) {
        if (lane < 60) {
          while (__hip_atomic_load(&tg[lane*32], __ATOMIC_RELAXED,
                                   __HIP_MEMORY_SCOPE_AGENT) < t)
            __builtin_amdgcn_s_sleep(1);
        }
        if (lane == 0) ((volatile int*)&hready)[0] = t;
      } else {
        while (((volatile int*)&hready)[0] < t) __builtin_amdgcn_s_sleep(1);
      }
      // one-shot bulk read from parity t&1: 608 float4, MALL-coherent
      if (tid < 304) {
        const float* p0 = hex0 + (size_t)(t&1)*4864 + tid*8;
        float4 v0, v1;
        asm volatile(
          "global_load_dwordx4 %0, %2, off sc0 sc1\n\t"
          "global_load_dwordx4 %1, %3, off sc0 sc1\n\t"
          "s_waitcnt vmcnt(0)"
          : "=v"(v0), "=v"(v1)
          : "v"(p0), "v"(p0 + 4)
          : "memory");
        float4* d = (float4*)&hls[tid*8];
        d[0] = v0; d[1] = v1;
      }
    }
    __syncthreads();                          // B1: hls ready
    // partial dot products (4 gate rows/wave broadcast-share each LDS word)
    float p[8];
    {
      const float4* h4 = (const float4*)hls;
      #pragma unroll
      for (int b=0;b<8;b++){
        const float4* hb = h4 + b*76 + s*5;   // 304 floats = 76 f4 per row
        float ax=0.f, ay=0.f, az=0.f, aw=0.f;
        #pragma unroll
        for (int q=0;q<5;q++){
          float4 hv = hb[q];
          ax = fmaf(w4[q].x, hv.x, ax);
          ay = fmaf(w4[q].y, hv.y, ay);
          az = fmaf(w4[q].z, hv.z, az);
          aw = fmaf(w4[q].w, hv.w, aw);
        }
        p[b] = (ax+ay)+(az+aw);
      }
    }
    // butterfly reduce-scatter over the 16 s-lanes
    #pragma unroll
    for (int b=0;b<8;b++) p[b] += __shfl_xor(p[b], 8, 64);
    float q4[4];
    #pragma unroll
    for (int b=0;b<4;b++){
      float mine = (s&4) ? p[b+4] : p[b];
      float oth  = (s&4) ? p[b]   : p[b+4];
      q4[b] = mine + __shfl_xor(oth, 4, 64);
    }
    float q2[2];
    #pragma unroll
    for (int b=0;b<2;b++){
      float mine = (s&2) ? q4[b+2] : q4[b];
      float oth  = (s&2) ? q4[b]   : q4[b+2];
      q2[b] = mine + __shfl_xor(oth, 2, 64);
    }
    float gv;
    {
      float mine = (s&1) ? q2[1] : q2[0];
      float oth  = (s&1) ? q2[0] : q2[1];
      gv = mine + __shfl_xor(oth, 1, 64) + xg_c;  // valid on s<8 (b=s)
    }
    // gather the 4 gates of (j=jj, b) in-wave
    {
      int bsel = lane & 7;
      float g_i = __shfl(gv,      bsel, 64);
      float g_f = __shfl(gv, 16 + bsel, 64);
      float g_g = __shfl(gv, 32 + bsel, 64);
      float g_o = __shfl(gv, 48 + bsel, 64);
      if (lane < 8) {
        int b = lane;
        float ig = sigm(g_i), fg = sigm(g_f), gg = tanhf(g_g), og = sigm(g_o);
        creg = fg * creg + ig * gg;
        float h = og * tanhf(creg);
        out[((size_t)(b*LL + tOrig))*600 + dir*HH + jj] = h;
        if (t+1 < LL)
          __hip_atomic_store(&hex0[(size_t)(((t+1)&1))*4864 + b*304 + jj], h,
                             __ATOMIC_RELAXED, __HIP_MEMORY_SCOPE_AGENT);
      }
    }
    __syncthreads();   // B2: drains vmcnt(0) -> out+hex stores complete
    if (t+1 < LL && tid == 0)
      __hip_atomic_store(&tg[wid*32], t+1,
                         __ATOMIC_RELAXED, __HIP_MEMORY_SCOPE_AGENT);
    xg_c = xg_n;
  }
}

// ---------------- K3a: U/V partial span projections (16 rows/block) — R8 verbatim ----------------
__global__ __launch_bounds__(320) void k_uv(
    const float* __restrict__ out, const float* __restrict__ sw1, float* __restrict__ UV)
{
  const int half = blockIdx.z;
  const int row0 = blockIdx.x * 16;
  __shared__ float As[16*20];
  __shared__ __align__(16) float Wt[16*172];
  const int tid = threadIdx.x;
  const int pg = tid / 20, ng = tid - (tid/20)*20;
  float acc[8] = {};
  for (int k0 = 0; k0 < 600; k0 += 16) {
    if (tid < 256) {
      int p = tid >> 4, kk = tid & 15;
      int k = k0 + kk;
      As[kk*20 + p] = (k < 600) ? out[(row0 + p)*600 + k] : 0.f;
    }
    for (int idx = tid; idx < 16*160; idx += 320) {
      int n = idx >> 4, kk = idx & 15;
      int k = k0 + kk;
      Wt[kk*172 + n] = (n < FFD && k < 600) ? sw1[n*1220 + half*600 + k] : 0.f;
    }
    __syncthreads();
    #pragma unroll
    for (int kk=0;kk<16;kk++){
      float a = As[kk*20 + pg];
      float4 w0 = *(const float4*)&Wt[kk*172 + ng*8];
      float4 w1 = *(const float4*)&Wt[kk*172 + ng*8 + 4];
      acc[0] = fmaf(a, w0.x, acc[0]);
      acc[1] = fmaf(a, w0.y, acc[1]);
      acc[2] = fmaf(a, w0.z, acc[2]);
      acc[3] = fmaf(a, w0.w, acc[3]);
      acc[4] = fmaf(a, w1.x, acc[4]);
      acc[5] = fmaf(a, w1.y, acc[5]);
      acc[6] = fmaf(a, w1.z, acc[6]);
      acc[7] = fmaf(a, w1.w, acc[7]);
    }
    __syncthreads();
  }
  {
    int row = row0 + pg;
    #pragma unroll
    for (int j=0;j<8;j++){
      int n = ng*8 + j;
      if (n < FFD) UV[row*300 + half*FFD + n] = acc[j];
    }
  }
}

// ---------------- K3b: span head, 32 spans/block — R8 verbatim ----------------
__global__ __launch_bounds__(320) void k_spanhead(
    const float* __restrict__ UV, const float* __restrict__ wcst,
    const float* __restrict__ sb1,
    const float* __restrict__ sw2, const float* __restrict__ sb2,
    const float* __restrict__ sw3, const float* __restrict__ sb3,
    float* __restrict__ sp)
{
  const int b  = blockIdx.y;
  const int s0 = blockIdx.x * 32;
  __shared__ __align__(16) float z1T[160*36];
  __shared__ __align__(16) float z2T[160*36];
  __shared__ __align__(16) float Wt[16*172];
  __shared__ float zf[128];
  __shared__ int sI[32], sJ[32], sW[32];
  const int tid = threadIdx.x;
  if (tid < 32) {
    int s = s0 + tid; int w = 1, i0 = 0;
    if (s < NSP) span_decode(s, w, i0);
    sI[tid] = i0; sJ[tid] = i0 + w - 1; sW[tid] = w;
  }
  __syncthreads();
  for (int idx = tid; idx < 32*160; idx += 320) {
    int p = idx / 160, k = idx - p*160;
    float v = 0.f;
    if (k < FFD && (s0 + p) < NSP) {
      v = UV[(b*LL + sI[p])*300 + k] + UV[(b*LL + sJ[p])*300 + FFD + k]
        + wcst[sW[p]*FFD + k] + sb1[k];
      v = fmaxf(v, 0.f);
    }
    z1T[k*36 + p] = v;
  }
  const int pg = tid / 20, ng = tid - (tid/20)*20;
  float acc[2][8] = {};
  for (int kt = 0; kt < 10; ++kt) {
    __syncthreads();
    for (int idx = tid; idx < 16*160; idx += 320) {
      int n = idx >> 4, kk = idx & 15;
      int k = kt*16 + kk;
      Wt[kk*172 + n] = (n < FFD && k < FFD) ? sw2[n*FFD + k] : 0.f;
    }
    __syncthreads();
    #pragma unroll
    for (int kk = 0; kk < 16; ++kk) {
      float2 a2 = *(const float2*)&z1T[(kt*16+kk)*36 + pg*2];
      float4 w0 = *(const float4*)&Wt[kk*172 + ng*8];
      float4 w1 = *(const float4*)&Wt[kk*172 + ng*8 + 4];
      float a_[2] = {a2.x, a2.y};
      float w_[8] = {w0.x,w0.y,w0.z,w0.w,w1.x,w1.y,w1.z,w1.w};
      #pragma unroll
      for (int i=0;i<2;i++)
        #pragma unroll
        for (int j=0;j<8;j++)
          acc[i][j] = fmaf(a_[i], w_[j], acc[i][j]);
    }
  }
  __syncthreads();
  #pragma unroll
  for (int j=0;j<8;j++){
    int n = ng*8 + j;
    float bn = (n < FFD) ? sb2[n] : 0.f;
    #pragma unroll
    for (int i=0;i<2;i++){
      float v = (n < FFD) ? fmaxf(acc[i][j] + bn, 0.f) : 0.f;
      z2T[n*36 + pg*2 + i] = v;
    }
  }
  __syncthreads();
  if (tid < 128) {
    int p = tid >> 2, c = tid & 3;
    if (c < 3 && (s0 + p) < NSP) {
      float a = sb3[c];
      for (int k=0;k<FFD;k++) a = fmaf(z2T[k*36 + p], sw3[c*FFD + k], a);
      zf[p*4 + c] = a;
    }
  }
  __syncthreads();
  if (tid < 32 && (s0 + tid) < NSP) {
    float z0 = zf[tid*4], z1 = zf[tid*4+1], z2 = zf[tid*4+2];
    float m = fmaxf(z0, fmaxf(z1, z2));
    float e0 = expf(z0-m), e1 = expf(z1-m), e2 = expf(z2-m);
    float inv = 1.f/(e0+e1+e2);
    int s = s0 + tid;
    sp[(b*NSP + s)*3 + 0] = e0*inv;
    sp[(b*NSP + s)*3 + 1] = e1*inv;
    sp[(b*NSP + s)*3 + 2] = e2*inv;
  }
}

// ---------------- K4: deterministic top-64 (ties -> smaller index) — R8 verbatim ----------------
__global__ __launch_bounds__(64) void k_topk(
    const float* __restrict__ sp, float* __restrict__ outT, float* __restrict__ outO,
    int* __restrict__ idxw)
{
  const int cls = blockIdx.x >> 3;   // 0: aspect(col1), 1: opinion(col2)
  const int b   = blockIdx.x & 7;
  const int lane = threadIdx.x;
  uint64_t key[10];
  #pragma unroll
  for (int q=0;q<10;q++){
    int s = lane + q*64;
    uint32_t bits = 0u;
    if (s < NSP) bits = __float_as_uint(sp[(b*NSP + s)*3 + 1 + cls]);
    key[q] = ((uint64_t)bits << 32) | (uint32_t)(1023 - s);
  }
  float* dst = cls ? outO : outT;
  for (int r = 0; r < NZK; ++r) {
    uint64_t best = key[0];
    #pragma unroll
    for (int q=1;q<10;q++) best = key[q] > best ? key[q] : best;
    #pragma unroll
    for (int off = 32; off > 0; off >>= 1) {
      uint64_t o = shfl_xor_u64(best, off);
      best = o > best ? o : best;
    }
    int sWin = 1023 - (int)(best & 0xFFFFFFFFu);
    if ((sWin & 63) == lane) {
      int qw = sWin >> 6;
      #pragma unroll
      for (int q=0;q<10;q++) if (q == qw) key[q] = 0;
    }
    if (lane == 0) {
      dst[b*NZK + r] = (float)sWin;
      idxw[cls*512 + b*NZK + r] = sWin;
    }
  }
}

// ---------------- K5a: Zt/Zo partials, K-split x2 — R8 verbatim ----------------
__global__ __launch_bounds__(320) void k_zto(
    const float* __restrict__ out, const float* __restrict__ wemb,
    const float* __restrict__ pw1, const int* __restrict__ idxw,
    float* __restrict__ ZTO)
{
  const int kh  = blockIdx.x >> 6;
  const int r6  = blockIdx.x & 63;
  const int cls = r6 >> 5;
  const int rem = r6 & 31;
  const int b = rem >> 2;
  const int i0 = (rem & 3) * 16;
  const int kbeg = kh ? 640 : 0;
  const int kend = kh ? 1232 : 640;
  __shared__ float As[16*20];
  __shared__ __align__(16) float Wt[16*172];
  __shared__ int sI[16], sJ[16], sW[16];
  const int tid = threadIdx.x;
  if (tid < 16) {
    int S = idxw[cls*512 + b*64 + i0 + tid];
    int w, i_; span_decode(S, w, i_);
    sI[tid] = i_; sJ[tid] = i_ + w - 1; sW[tid] = w;
  }
  const int pg = tid / 20, ng = tid - (tid/20)*20;
  float acc[8] = {};
  __syncthreads();
  for (int k0 = kbeg; k0 < kend; k0 += 16) {
    if (tid < 256) {
      int p = tid >> 4, kk = tid & 15;
      int k = k0 + kk;
      float v = 0.f;
      if      (k < 600)  v = out[(b*LL + sI[p])*600 + k];
      else if (k < 1200) v = out[(b*LL + sJ[p])*600 + (k - 600)];
      else if (k < 1220) v = wemb[sW[p]*20 + (k - 1200)];
      As[kk*20 + p] = v;
    }
    for (int idx = tid; idx < 16*160; idx += 320) {
      int n = idx >> 4, kk = idx & 15;
      int k = k0 + kk;
      Wt[kk*172 + n] = (n < FFD && k < 1220) ? pw1[n*2568 + cls*1220 + k] : 0.f;
    }
    __syncthreads();
    #pragma unroll
    for (int kk=0;kk<16;kk++){
      float a = As[kk*20 + pg];
      float4 w0 = *(const float4*)&Wt[kk*172 + ng*8];
      float4 w1 = *(const float4*)&Wt[kk*172 + ng*8 + 4];
      acc[0] = fmaf(a, w0.x, acc[0]);
      acc[1] = fmaf(a, w0.y, acc[1]);
      acc[2] = fmaf(a, w0.z, acc[2]);
      acc[3] = fmaf(a, w0.w, acc[3]);
      acc[4] = fmaf(a, w1.x, acc[4]);
      acc[5] = fmaf(a, w1.y, acc[5]);
      acc[6] = fmaf(a, w1.z, acc[6]);
      acc[7] = fmaf(a, w1.w, acc[7]);
    }
    __syncthreads();
  }
  #pragma unroll
  for (int j=0;j<8;j++){
    int n = ng*8 + j;
    if (n < FFD) ZTO[(size_t)kh*153600 + (cls*512 + b*64 + i0 + pg)*FFD + n] = acc[j];
  }
}

// ---------------- K5b: pair head (sums both ZTO K-halves) — R8 verbatim ----------------
__global__ __launch_bounds__(320) void k_pairhead(
    const float* __restrict__ ZTO, const float* __restrict__ Zd,
    const float* __restrict__ pb1,
    const float* __restrict__ pw2, const float* __restrict__ pb2,
    const float* __restrict__ pw3, const float* __restrict__ pb3,
    const int* __restrict__ idxw,
    float* __restrict__ cp)
{
  const int b  = blockIdx.y;
  const int ti = blockIdx.x;
  __shared__ __align__(16) float z1T[160*68];
  __shared__ __align__(16) float z2T[160*68];
  __shared__ __align__(16) float Wt[16*172];
  __shared__ float zf[256];
  __shared__ int oDist[64];
  const int tid = threadIdx.x;
  const int tS = idxw[b*64 + ti];
  int wT, iT; span_decode(tS, wT, iT);
  const int aT = iT, bT = iT + wT - 1;
  if (tid < 64) {
    int oS = idxw[512 + b*64 + tid];
    int wO, iO; span_decode(oS, wO, iO);
    int d1 = bT - iO;            if (d1 < 0) d1 = -d1;
    int d2 = aT - (iO + wO - 1); if (d2 < 0) d2 = -d2;
    oDist[tid] = d1 < d2 ? d1 : d2;
  }
  __syncthreads();
  const float* Zt0 = ZTO + (b*64 + ti)*FFD;
  const float* Zt1 = Zt0 + 153600;
  for (int idx = tid; idx < 64*160; idx += 320) {
    int p = idx / 160, k = idx - p*160;
    float v = 0.f;
    if (k < FFD) {
      int os = (512 + b*64 + p)*FFD + k;
      v = Zt0[k] + Zt1[k] + ZTO[os] + ZTO[153600 + os] + Zd[oDist[p]*FFD + k] + pb1[k];
      v = fmaxf(v, 0.f);
    }
    z1T[k*68 + p] = v;
  }
  const int pg = tid / 20, ng = tid - (tid/20)*20;
  float acc[4][8] = {};
  for (int kt = 0; kt < 10; ++kt) {
    __syncthreads();
    for (int idx = tid; idx < 16*160; idx += 320) {
      int n = idx >> 4, kk = idx & 15;
      int k = kt*16 + kk;
      Wt[kk*172 + n] = (n < FFD && k < FFD) ? pw2[n*FFD + k] : 0.f;
    }
    __syncthreads();
    #pragma unroll
    for (int kk = 0; kk < 16; ++kk) {
      float4 a4 = *(const float4*)&z1T[(kt*16+kk)*68 + pg*4];
      float4 w0 = *(const float4*)&Wt[kk*172 + ng*8];
      float4 w1 = *(const float4*)&Wt[kk*172 + ng*8 + 4];
      float a_[4] = {a4.x,a4.y,a4.z,a4.w};
      float w_[8] = {w0.x,w0.y,w0.z,w0.w,w1.x,w1.y,w1.z,w1.w};
      #pragma unroll
      for (int i=0;i<4;i++)
        #pragma unroll
        for (int j=0;j<8;j++)
          acc[i][j] = fmaf(a_[i], w_[j], acc[i][j]);
    }
  }
  __syncthreads();
  #pragma unroll
  for (int j=0;j<8;j++){
    int n = ng*8 + j;
    float bn = (n < FFD) ? pb2[n] : 0.f;
    #pragma unroll
    for (int i=0;i<4;i++){
      float v = (n < FFD) ? fmaxf(acc[i][j] + bn, 0.f) : 0.f;
      z2T[n*68 + pg*4 + i] = v;
    }
  }
  __syncthreads();
  if (tid < 256) {
    int p = tid >> 2, c = tid & 3;
    float a = pb3[c];
    for (int k=0;k<FFD;k++) a = fmaf(z2T[k*68 + p], pw3[c*FFD + k], a);
    zf[tid] = a;
  }
  __syncthreads();
  if (tid < 64) {
    float z0 = zf[tid*4], z1 = zf[tid*4+1], z2 = zf[tid*4+2], z3 = zf[tid*4+3];
    float m = fmaxf(fmaxf(z0,z1), fmaxf(z2,z3));
    float e0 = expf(z0-m), e1 = expf(z1-m), e2 = expf(z2-m), e3 = expf(z3-m);
    float inv = 1.f/(e0+e1+e2+e3);
    float4 o4 = make_float4(e0*inv, e1*inv, e2*inv, e3*inv);
    *(float4*)&cp[(size_t)((b*4096 + ti*64 + tid))*4] = o4;
  }
}

// ---------------- launch ----------------
extern "C" void kernel_launch(void* const* d_in, const int* in_sizes, int n_in,
                              void* d_out, int out_size, void* d_ws, size_t ws_size,
                              hipStream_t stream) {
  const float* x    = (const float*)d_in[0];
  const float* WihF = (const float*)d_in[1];
  const float* WhhF = (const float*)d_in[2];
  const float* bihF = (const float*)d_in[3];
  const float* bhhF = (const float*)d_in[4];
  const float* WihB = (const float*)d_in[5];
  const float* WhhB = (const float*)d_in[6];
  const float* bihB = (const float*)d_in[7];
  const float* bhhB = (const float*)d_in[8];
  const float* wemb = (const float*)d_in[9];
  const float* demb = (const float*)d_in[10];
  const float* sw1  = (const float*)d_in[11];
  const float* sb1  = (const float*)d_in[12];
  const float* sw2  = (const float*)d_in[13];
  const float* sb2  = (const float*)d_in[14];
  const float* sw3  = (const float*)d_in[15];
  const float* sb3  = (const float*)d_in[16];
  const float* pw1  = (const float*)d_in[17];
  const float* pb1  = (const float*)d_in[18];
  const float* pw2  = (const float*)d_in[19];
  const float* pb2  = (const float*)d_in[20];
  const float* pw3  = (const float*)d_in[21];
  const float* pb3  = (const float*)d_in[22];

  uint8_t* wsb = (uint8_t*)d_ws;
  int*   tags  = (int*)wsb;                        // [2][60] stride-32 (15.4 KB)
  float* hexf  = (float*)(wsb + 16384);            // [2][2][8][304] floats (38.9 KB)
  float* xg    = (float*)(wsb + 131072);           // [2][128][1200][8] = 2457600 f
  float* outh  = xg   + 2457600;                   // [8][128][600]     = 614400 f
  float* UV    = outh + 614400;                    // [1024][300]       = 307200 f
  float* wcst  = UV   + 307200;                    // [6][150]          = 900 f
  float* Zd    = wcst + 900;                       // [256][150]        = 38400 f
  float* ZTO   = Zd   + 38400;                     // [2][1024][150]    = 307200 f
  int*  idxw   = (int*)(ZTO + 307200);             // [2][8][64]        = 1024 i

  float* o   = (float*)d_out;
  float* spO = o;              // [8][630][3]  = 15120
  float* cpO = o + 15120;      // [8][4096][4] = 131072
  float* tO  = o + 146192;     // [8][64]
  float* oO  = o + 146704;     // [8][64]

  k_xg      <<<dim3(19,16,3), 256, 0, stream>>>(x, WihF, bihF, bhhF, WihB, bihB, bhhB, xg, tags,
                                                sw1, wemb, wcst, pw1, demb, Zd);
  k_lstm    <<<dim3(2*WPD), 320, 0, stream>>>(WhhF, WhhB, xg, hexf, tags, outh);
  k_uv      <<<dim3(64,1,2), 320, 0, stream>>>(outh, sw1, UV);
  k_spanhead<<<dim3(20,8), 320, 0, stream>>>(UV, wcst, sb1, sw2, sb2, sw3, sb3, spO);
  k_topk    <<<dim3(16),  64, 0, stream>>>(spO, tO, oO, idxw);
  k_zto     <<<dim3(128), 320, 0, stream>>>(outh, wemb, pw1, idxw, ZTO);
  k_pairhead<<<dim3(64,8), 320, 0, stream>>>(ZTO, Zd, pb1, pw2, pb2, pw3, pb3, idxw, cpO);
}